// Round 8
// baseline (523.346 us; speedup 1.0000x reference)
//
#include <hip/hip_runtime.h>

#define DEV static __device__ __forceinline__

typedef short bf16x8 __attribute__((ext_vector_type(8)));
typedef float floatx4 __attribute__((ext_vector_type(4)));
typedef unsigned short ushort4v __attribute__((ext_vector_type(4)));
typedef unsigned short ushort8v __attribute__((ext_vector_type(8)));

DEV unsigned short f32_bf16(float f) {
  unsigned int u = __builtin_bit_cast(unsigned int, f);
  u = u + 0x7fffu + ((u >> 16) & 1u);
  return (unsigned short)(u >> 16);
}
DEV float bf2f(unsigned short u) {
  unsigned int v = ((unsigned int)u) << 16;
  return __builtin_bit_cast(float, v);
}
DEV float sigmoidf_(float x) { return 1.0f / (1.0f + __expf(-x)); }
DEV float siluf_(float x) { return x * sigmoidf_(x); }

#define GLD_LDS16(g, l)                                                              \
  __builtin_amdgcn_global_load_lds((const __attribute__((address_space(1))) void*)(g), \
                                   (__attribute__((address_space(3))) void*)(l), 16, 0, 0)

// ---------------------------------------------------------------------------
// Pipelined MFMA GEMM: C[M,N] = A[M,K] @ B[N,K]^T, bf16 in, 128xBN block tile.
// BN per dispatch so grid >= 2 blocks/CU (R7-verified). DOUBLE-buffered LDS,
// 2-barrier loop, counted vmcnt. Epilogue (MODE 1/2): f32 acc -> LDS
// [32][BN+4] four 32-row passes -> ushort8 stores. MODE 0: fp32 store.
// ---------------------------------------------------------------------------
template <int MODE, int BN>
__global__ __launch_bounds__(256) void gemm128(
    const unsigned short* __restrict__ A, const unsigned short* __restrict__ B,
    void* __restrict__ Cv, const unsigned short* __restrict__ other,
    int K, int lda, int ldb, int ldc, long long bsA, long long bsB, long long bsC) {
  constexpr int NBG = BN / 64;           // B gload_lds per wave per stage (2|4)
  constexpr int NJ = BN / 32;            // j-fragments per wave (4|8)
  constexpr int BUFSZ = 4096 + BN * 32;  // ushorts per buffer (A 128x32 + B BNx32)
  __shared__ unsigned short S[2 * BUFSZ];
  A += (long long)blockIdx.z * bsA;
  B += (long long)blockIdx.z * bsB;
  const long long coff = (long long)blockIdx.z * bsC;
  const int tid = threadIdx.x;
  const int w = tid >> 6, lane = tid & 63;

  // GM=4 supertile swizzle: consecutive blocks walk M within a 4-row group.
  const int nbx = gridDim.x, nby = gridDim.y;
  const int GM = 4;
  int bid = blockIdx.y * nbx + blockIdx.x;
  int gid = bid / (GM * nbx);
  int rem = bid - gid * (GM * nbx);
  int gsz = min(GM, nby - gid * GM);
  int mtile = gid * GM + rem % gsz;
  int ntile = rem / gsz;
  const int m0 = mtile << 7, n0 = ntile * BN;

  const int srow = lane >> 2;
  const int schunk = ((lane & 3) ^ (srow & 3)) * 8;  // pre-swizzled global src
  const unsigned short* ag0 = A + (long long)(m0 + w * 32 + srow) * lda + schunk;
  const unsigned short* ag1 = ag0 + (long long)16 * lda;
  const unsigned short* bgp[NBG];
#pragma unroll
  for (int ii = 0; ii < NBG; ++ii)
    bgp[ii] = B + (long long)(n0 + w * (BN / 4) + srow + 16 * ii) * ldb + schunk;

  auto STAGE = [&](int buf, int k0) {
    unsigned short* as_ = S + buf * BUFSZ;
    unsigned short* bs_ = as_ + 4096;
    GLD_LDS16(ag0 + k0, as_ + w * 1024 + lane * 8);
    GLD_LDS16(ag1 + k0, as_ + w * 1024 + lane * 8 + 512);
#pragma unroll
    for (int ii = 0; ii < NBG; ++ii)
      GLD_LDS16(bgp[ii] + k0, bs_ + w * (NBG * 512) + ii * 512 + lane * 8);
  };

  const int wr = (w >> 1) << 6;
  const int wc = (w & 1) * (BN / 2);
  const int fr = lane & 15;
  const int slot = (((lane >> 4) ^ (fr & 3))) << 3;
  const int r0 = (lane >> 4) << 2;

  floatx4 acc[4][NJ];
#pragma unroll
  for (int i = 0; i < 4; ++i)
#pragma unroll
    for (int j = 0; j < NJ; ++j) acc[i][j] = (floatx4){0.f, 0.f, 0.f, 0.f};

  const int nsteps = K >> 5;
  STAGE(0, 0);
  if (nsteps > 1) STAGE(1, 32);

  for (int t = 0; t < nsteps; ++t) {
    if (t < nsteps - 1) {
      if constexpr (NBG == 2) {
        asm volatile("s_waitcnt vmcnt(4)" ::: "memory");
      } else {
        asm volatile("s_waitcnt vmcnt(6)" ::: "memory");
      }
    } else {
      asm volatile("s_waitcnt vmcnt(0)" ::: "memory");
    }
    __builtin_amdgcn_s_barrier();
    __builtin_amdgcn_sched_barrier(0);
    const unsigned short* Ab = S + (t & 1) * BUFSZ;
    const unsigned short* Bb = Ab + 4096;
    bf16x8 af[4], bf_[NJ];
#pragma unroll
    for (int i = 0; i < 4; ++i)
      af[i] = *(const bf16x8*)(Ab + (wr + i * 16 + fr) * 32 + slot);
#pragma unroll
    for (int j = 0; j < NJ; ++j)
      bf_[j] = *(const bf16x8*)(Bb + (wc + j * 16 + fr) * 32 + slot);
#pragma unroll
    for (int i = 0; i < 4; ++i)
#pragma unroll
      for (int j = 0; j < NJ; ++j)
        acc[i][j] = __builtin_amdgcn_mfma_f32_16x16x32_bf16(af[i], bf_[j], acc[i][j], 0, 0, 0);
    __builtin_amdgcn_sched_barrier(0);
    __builtin_amdgcn_s_barrier();
    if (t + 2 < nsteps) STAGE(t & 1, (t + 2) * 32);
  }

  if constexpr (MODE == 0) {
#pragma unroll
    for (int i = 0; i < 4; ++i) {
#pragma unroll
      for (int j = 0; j < NJ; ++j) {
        long long base = (long long)(m0 + wr + i * 16 + r0) * ldc + (n0 + wc + j * 16 + fr);
#pragma unroll
        for (int r = 0; r < 4; ++r) {
          ((float*)Cv)[coff + base + (long long)r * ldc] = acc[i][j][r];
        }
      }
    }
  } else {
    constexpr int PAD = BN + 4;
    float* scr = (float*)S;
    const int row_l = tid >> 3;      // 0..31
    const int col0 = (tid & 7) * 8;  // 0..56 step 8
    __syncthreads();
#pragma unroll
    for (int pass = 0; pass < 4; ++pass) {
      if ((w >> 1) == (pass >> 1)) {
#pragma unroll
        for (int ii = 0; ii < 2; ++ii) {
          int i = (pass & 1) * 2 + ii;
          int rl = i * 16 + r0 - (pass & 1) * 32;  // 0..31
#pragma unroll
          for (int j = 0; j < NJ; ++j) {
            int col = wc + j * 16 + fr;
#pragma unroll
            for (int r = 0; r < 4; ++r) scr[(rl + r) * PAD + col] = acc[i][j][r];
          }
        }
      }
      __syncthreads();
      long long grow = m0 + pass * 32 + row_l;
      long long gbase = coff + grow * ldc + n0;
      const float* srow_p = scr + row_l * PAD;
#pragma unroll
      for (int k = 0; k < BN / 64; ++k) {
        int col = col0 + k * 64;
        float v[8];
        *(float4*)&v[0] = *(const float4*)(srow_p + col);
        *(float4*)&v[4] = *(const float4*)(srow_p + col + 4);
        ushort8v o;
        if constexpr (MODE == 2) {
          ushort8v uo = *(const ushort8v*)(other + gbase + col);
#pragma unroll
          for (int e = 0; e < 8; ++e) o[e] = f32_bf16(siluf_(v[e]) * bf2f(uo[e]));
        } else {
#pragma unroll
          for (int e = 0; e < 8; ++e) o[e] = f32_bf16(v[e]);
        }
        *(ushort8v*)((unsigned short*)Cv + gbase + col) = o;
      }
      __syncthreads();
    }
  }
}

// ---------------------------------------------------------------------------
// small GEMM (direct-from-global), used only for the N=32 dt projection.
// ---------------------------------------------------------------------------
template <int WM>
__global__ __launch_bounds__(256) void gemm_small_nt(
    const unsigned short* __restrict__ A, const unsigned short* __restrict__ B,
    float* __restrict__ C, int M, int N, int K, int lda, int ldb, int ldc) {
  const int w = threadIdx.x >> 6;
  const int lane = threadIdx.x & 63;
  const int lm = lane & 15;
  const int ko = (lane >> 4) << 3;
  const int bn0 = blockIdx.x << 6;
  const int m_base = blockIdx.y * (WM * 64) + w * (WM * 16);

  const unsigned short* arow[WM];
#pragma unroll
  for (int i = 0; i < WM; ++i) arow[i] = A + (long long)(m_base + i * 16 + lm) * lda + ko;
  int nv = (N - bn0) >> 4;
  nv = nv > 4 ? 4 : nv;
  const unsigned short* brow[4];
#pragma unroll
  for (int j = 0; j < 4; ++j) {
    int nr = bn0 + j * 16 + lm;
    brow[j] = B + (long long)(j < nv ? nr : 0) * ldb + ko;
  }
  floatx4 acc[WM][4];
#pragma unroll
  for (int i = 0; i < WM; ++i)
#pragma unroll
    for (int j = 0; j < 4; ++j) acc[i][j] = (floatx4){0.f, 0.f, 0.f, 0.f};
  for (int k0 = 0; k0 < K; k0 += 32) {
    bf16x8 a[WM];
#pragma unroll
    for (int i = 0; i < WM; ++i) a[i] = *(const bf16x8*)(arow[i] + k0);
#pragma unroll
    for (int j = 0; j < 4; ++j) {
      if (j < nv) {
        bf16x8 b = *(const bf16x8*)(brow[j] + k0);
#pragma unroll
        for (int i = 0; i < WM; ++i)
          acc[i][j] = __builtin_amdgcn_mfma_f32_16x16x32_bf16(a[i], b, acc[i][j], 0, 0, 0);
      }
    }
  }
  const int r0 = (lane >> 4) << 2;
#pragma unroll
  for (int i = 0; i < WM; ++i)
#pragma unroll
    for (int j = 0; j < 4; ++j)
      if (j < nv) {
        int col = bn0 + j * 16 + lm;
        long long base = (long long)(m_base + i * 16 + r0) * ldc + col;
#pragma unroll
        for (int r = 0; r < 4; ++r) C[base + (long long)r * ldc] = acc[i][j][r];
      }
}

// ---------------------------------------------------------------------------
// All weight conversions fused into one kernel (5 ranges, float4 units).
// ---------------------------------------------------------------------------
__global__ __launch_bounds__(256) void wconv_all_k(
    const float* __restrict__ w_in, const float* __restrict__ w_gate,
    const float* __restrict__ w_up, const float* __restrict__ w_down,
    const float* __restrict__ w_out, unsigned short* __restrict__ d_in_,
    unsigned short* __restrict__ d_gate, unsigned short* __restrict__ d_up,
    unsigned short* __restrict__ d_down, unsigned short* __restrict__ d_out_) {
  long long j = (long long)blockIdx.x * 256 + threadIdx.x;
  const float* src;
  unsigned short* dst;
  if (j < 1122304) {
    src = w_in; dst = d_in_;
  } else if ((j -= 1122304) < 1048576) {
    src = w_gate; dst = d_gate;
  } else if ((j -= 1048576) < 1048576) {
    src = w_up; dst = d_up;
  } else if ((j -= 1048576) < 1048576) {
    src = w_down; dst = d_down;
  } else if ((j -= 1048576) < 524288) {
    src = w_out; dst = d_out_;
  } else {
    return;
  }
  float4 v = ((const float4*)src)[j];
  ushort4v o = {f32_bf16(v.x), f32_bf16(v.y), f32_bf16(v.z), f32_bf16(v.w)};
  ((ushort4v*)dst)[j] = o;
}

__global__ __launch_bounds__(256) void zero_out_k(float* __restrict__ o, long long n) {
  long long i = (long long)blockIdx.x * 256 + threadIdx.x;
  if (i < n) o[i] = 0.f;
}

// ---------------------------------------------------------------------------
__global__ __launch_bounds__(256) void rmsnorm1024_bf16_k(const float* __restrict__ x,
                                                          const float* __restrict__ w,
                                                          unsigned short* __restrict__ out,
                                                          float eps) {
  long long row = blockIdx.x;
  int t = threadIdx.x;
  float4 v = ((const float4*)(x + row * 1024))[t];
  float ss = v.x * v.x + v.y * v.y + v.z * v.z + v.w * v.w;
  __shared__ float red[4];
#pragma unroll
  for (int o = 32; o > 0; o >>= 1) ss += __shfl_down(ss, o, 64);
  if ((t & 63) == 0) red[t >> 6] = ss;
  __syncthreads();
  float tot = red[0] + red[1] + red[2] + red[3];
  float sc = rsqrtf(tot * (1.0f / 1024.0f) + eps);
  float4 wv = ((const float4*)w)[t];
  ushort4v o = {f32_bf16(v.x * sc * wv.x), f32_bf16(v.y * sc * wv.y),
                f32_bf16(v.z * sc * wv.z), f32_bf16(v.w * sc * wv.w)};
  ((ushort4v*)(out + row * 1024))[t] = o;
}

// ---------------------------------------------------------------------------
// Fused: mh = hs + sum_{p<np} parts[p]; h2 = bf16(rmsnorm(mh) * w). 1024 cols.
// ---------------------------------------------------------------------------
__global__ __launch_bounds__(256) void add_rmsnorm_k(const float* __restrict__ hs,
                                                     const float* __restrict__ parts,
                                                     long long pstride, int np,
                                                     const float* __restrict__ w,
                                                     float* __restrict__ mh,
                                                     unsigned short* __restrict__ h2, float eps) {
  long long row = blockIdx.x;
  int t = threadIdx.x;
  float4 v = ((const float4*)(hs + row * 1024))[t];
  for (int p = 0; p < np; ++p) {
    float4 u = ((const float4*)(parts + p * pstride + row * 1024))[t];
    v.x += u.x;
    v.y += u.y;
    v.z += u.z;
    v.w += u.w;
  }
  ((float4*)(mh + row * 1024))[t] = v;
  float ss = v.x * v.x + v.y * v.y + v.z * v.z + v.w * v.w;
  __shared__ float red[4];
#pragma unroll
  for (int o = 32; o > 0; o >>= 1) ss += __shfl_down(ss, o, 64);
  if ((t & 63) == 0) red[t >> 6] = ss;
  __syncthreads();
  float tot = red[0] + red[1] + red[2] + red[3];
  float sc = rsqrtf(tot * (1.0f / 1024.0f) + eps);
  float4 wv = ((const float4*)w)[t];
  ushort4v o = {f32_bf16(v.x * sc * wv.x), f32_bf16(v.y * sc * wv.y),
                f32_bf16(v.z * sc * wv.z), f32_bf16(v.w * sc * wv.w)};
  ((ushort4v*)(h2 + row * 1024))[t] = o;
}

// ---------------------------------------------------------------------------
__global__ __launch_bounds__(256) void addn_f32_k(const float* __restrict__ a,
                                                  const float* __restrict__ parts,
                                                  long long pstride, int np,
                                                  float* __restrict__ o, long long n4) {
  long long i = (long long)blockIdx.x * 256 + threadIdx.x;
  if (i < n4) {
    float4 x = ((const float4*)a)[i];
    for (int p = 0; p < np; ++p) {
      float4 u = ((const float4*)(parts + p * pstride))[i];
      x.x += u.x;
      x.y += u.y;
      x.z += u.z;
      x.w += u.w;
    }
    ((float4*)o)[i] = x;
  }
}

// ---------------------------------------------------------------------------
__global__ __launch_bounds__(256) void gated_rmsnorm2048_k(const unsigned short* __restrict__ y,
                                                           const unsigned short* __restrict__ z,
                                                           const float* __restrict__ w,
                                                           unsigned short* __restrict__ out,
                                                           float eps) {
  long long row = blockIdx.x;
  int t = threadIdx.x;
  ushort8v yv = ((const ushort8v*)(y + row * 2048))[t];
  ushort8v zv = ((const ushort8v*)(z + row * 2048))[t];
  float g[8];
  float ss = 0.f;
#pragma unroll
  for (int j = 0; j < 8; ++j) {
    g[j] = bf2f(yv[j]) * siluf_(bf2f(zv[j]));
    ss += g[j] * g[j];
  }
  __shared__ float red[4];
#pragma unroll
  for (int o = 32; o > 0; o >>= 1) ss += __shfl_down(ss, o, 64);
  if ((t & 63) == 0) red[t >> 6] = ss;
  __syncthreads();
  float tot = red[0] + red[1] + red[2] + red[3];
  float sc = rsqrtf(tot * (1.0f / 2048.0f) + eps);
  float ww[8];
  *(float4*)&ww[0] = ((const float4*)w)[2 * t];
  *(float4*)&ww[4] = ((const float4*)w)[2 * t + 1];
  ushort8v o;
#pragma unroll
  for (int j = 0; j < 8; ++j) o[j] = f32_bf16(g[j] * sc * ww[j]);
  ((ushort8v*)(out + row * 2048))[t] = o;
}

// ---------------------------------------------------------------------------
// conv + silu: flat (m, cb) grid, exactly 1 vec8 work item per thread
// (old layout ran 288 items on 256 threads -> half the block idled pass 2).
// ---------------------------------------------------------------------------
__global__ __launch_bounds__(256) void conv_silu_k(const unsigned short* __restrict__ xraw,
                                                   const float* __restrict__ wconv,
                                                   const float* __restrict__ bconv,
                                                   unsigned short* __restrict__ xBC) {
  long long f = (long long)blockIdx.x * 256 + threadIdx.x;
  if (f >= 4096LL * 288) return;
  int m = (int)(f / 288);
  int cb = (int)(f - (long long)m * 288);
  int l = m & 2047;
  int ch0 = cb << 3;
  float acc[8];
  float4 bc0 = ((const float4*)bconv)[cb * 2];
  float4 bc1 = ((const float4*)bconv)[cb * 2 + 1];
  acc[0] = bc0.x; acc[1] = bc0.y; acc[2] = bc0.z; acc[3] = bc0.w;
  acc[4] = bc1.x; acc[5] = bc1.y; acc[6] = bc1.z; acc[7] = bc1.w;
  float4 wv[8];
#pragma unroll
  for (int j = 0; j < 8; ++j) wv[j] = ((const float4*)wconv)[ch0 + j];
#pragma unroll
  for (int k = 0; k < 4; ++k) {
    int lk = l + k - 3;
    if (lk >= 0) {
      ushort8v xv = *(const ushort8v*)(xraw + (long long)(m + k - 3) * 2304 + ch0);
      acc[0] += bf2f(xv[0]) * ((const float*)&wv[0])[k];
      acc[1] += bf2f(xv[1]) * ((const float*)&wv[1])[k];
      acc[2] += bf2f(xv[2]) * ((const float*)&wv[2])[k];
      acc[3] += bf2f(xv[3]) * ((const float*)&wv[3])[k];
      acc[4] += bf2f(xv[4]) * ((const float*)&wv[4])[k];
      acc[5] += bf2f(xv[5]) * ((const float*)&wv[5])[k];
      acc[6] += bf2f(xv[6]) * ((const float*)&wv[6])[k];
      acc[7] += bf2f(xv[7]) * ((const float*)&wv[7])[k];
    }
  }
  ushort8v o;
#pragma unroll
  for (int j = 0; j < 8; ++j) o[j] = f32_bf16(siluf_(acc[j]));
  *(ushort8v*)(xBC + (long long)m * 2304 + ch0) = o;
}

// ---------------------------------------------------------------------------
// Fused dt softplus + dA cumsum.
// ---------------------------------------------------------------------------
__global__ __launch_bounds__(128) void dA_cumsum_k(const float* __restrict__ dtraw,
                                                   const float* __restrict__ dt_bias,
                                                   const float* __restrict__ A_log,
                                                   float* __restrict__ dt_s,
                                                   float* __restrict__ dA_cs) {
  int bi = blockIdx.x;
  int c = bi & 15, h = (bi >> 4) & 31, b = bi >> 9;
  int q = threadIdx.x;
  long long idx = ((long long)(b * 2048 + c * 128 + q)) * 32 + h;
  float xv = dtraw[idx] + dt_bias[h];
  float sp = xv > 20.f ? xv : log1pf(expf(xv));
  dt_s[idx] = sp;
  float A = -expf(A_log[h]);
  float v = sp * A;
  __shared__ float sbuf[128];
  sbuf[q] = v;
  __syncthreads();
  for (int off = 1; off < 128; off <<= 1) {
    float tv = (q >= off) ? sbuf[q - off] : 0.f;
    __syncthreads();
    sbuf[q] += tv;
    __syncthreads();
  }
  dA_cs[(long long)bi * 128 + q] = sbuf[q];
}

// ---------------------------------------------------------------------------
// S3 (MFMA): Y_diag -> y bf16, local states -> states bf16.
// R8: vectorized Mz G-fill (ds_write_b128), Y/states outputs routed through
// LDS (reuse Mz as f32 scratch) -> ushort8 coalesced global stores.
// ---------------------------------------------------------------------------
__global__ __launch_bounds__(256) void ssd_diag_states_k(
    const unsigned short* __restrict__ xBC, const float* __restrict__ dt_s,
    const float* __restrict__ dA_cs, const unsigned short* __restrict__ G,
    unsigned short* __restrict__ y, unsigned short* __restrict__ states) {
  __shared__ unsigned short Mz[128 * 136];  // 34816 B; reused as f32 scratch
  __shared__ unsigned short xdT[64 * 136];
  __shared__ float Acs[128];
  __shared__ float wdec[128];
  const int bx = blockIdx.x;
  const int h = bx & 31, c = (bx >> 5) & 15, b = bx >> 9;
  const int t = threadIdx.x;
  const int w = t >> 6, lane = t & 63, fr = lane & 15, hi = lane >> 4;
  const long long rowbase = (long long)b * 2048 + c * 128;
  const long long abase = ((long long)((b * 32 + h) * 16 + c)) << 7;

  if (t < 128) {
    float a = dA_cs[abase + t];
    Acs[t] = a;
    wdec[t] = __expf(dA_cs[abase + 127] - a);
  }
  {
    int s = t >> 1, p0 = (t & 1) * 32;
    float dtv = dt_s[(rowbase + s) * 32 + h];
    const ushort8v* xv = (const ushort8v*)(xBC + (rowbase + s) * 2304 + h * 64 + p0);
#pragma unroll
    for (int i = 0; i < 4; ++i) {
      ushort8v vv = xv[i];
#pragma unroll
      for (int j = 0; j < 8; ++j) xdT[(p0 + i * 8 + j) * 136 + s] = f32_bf16(bf2f(vv[j]) * dtv);
    }
  }
  __syncthreads();
  {
    int q = t >> 1, s0 = (t & 1) * 64;
    float aq = Acs[q];
    const ushort8v* gv =
        (const ushort8v*)(G + (((long long)(b * 16 + c)) * 128 + q) * 128 + s0);
#pragma unroll
    for (int i = 0; i < 8; ++i) {
      ushort8v gg = gv[i];
      ushort8v mo;
#pragma unroll
      for (int j = 0; j < 8; ++j) {
        int s = s0 + i * 8 + j;
        float m = (s <= q) ? bf2f(gg[j]) * __expf(aq - Acs[s]) : 0.f;
        mo[j] = f32_bf16(m);
      }
      *(ushort8v*)(Mz + q * 136 + s0 + i * 8) = mo;  // one b128 per 8 elems
    }
  }
  __syncthreads();
  const int q0 = w << 5;
  {
    floatx4 acc[2][4];
#pragma unroll
    for (int i = 0; i < 2; ++i)
#pragma unroll
      for (int j = 0; j < 4; ++j) acc[i][j] = (floatx4){0.f, 0.f, 0.f, 0.f};
#pragma unroll
    for (int k0 = 0; k0 < 128; k0 += 32) {
      int kk = k0 + hi * 8;
      bf16x8 a0 = *(const bf16x8*)(Mz + (q0 + fr) * 136 + kk);
      bf16x8 a1 = *(const bf16x8*)(Mz + (q0 + 16 + fr) * 136 + kk);
      bf16x8 bf_[4];
#pragma unroll
      for (int j = 0; j < 4; ++j) bf_[j] = *(const bf16x8*)(xdT + (j * 16 + fr) * 136 + kk);
#pragma unroll
      for (int j = 0; j < 4; ++j) {
        acc[0][j] = __builtin_amdgcn_mfma_f32_16x16x32_bf16(a0, bf_[j], acc[0][j], 0, 0, 0);
        acc[1][j] = __builtin_amdgcn_mfma_f32_16x16x32_bf16(a1, bf_[j], acc[1][j], 0, 0, 0);
      }
    }
    // Y epilogue: acc -> LDS [128][68] f32 -> ushort8 stores.
    __syncthreads();  // all waves done reading Mz for Y
    float* scr = (float*)Mz;
#pragma unroll
    for (int i = 0; i < 2; ++i)
#pragma unroll
      for (int r = 0; r < 4; ++r) {
        int q = q0 + i * 16 + hi * 4 + r;
#pragma unroll
        for (int j = 0; j < 4; ++j) scr[q * 68 + j * 16 + fr] = acc[i][j][r];
      }
    __syncthreads();
    {
      int row = t >> 1, colh = (t & 1) * 32;
      unsigned short* yrow = y + (rowbase + row) * 2048 + h * 64 + colh;
      const float* sp = scr + row * 68 + colh;
#pragma unroll
      for (int k = 0; k < 4; ++k) {
        float4 v0 = *(const float4*)(sp + k * 8);
        float4 v1 = *(const float4*)(sp + k * 8 + 4);
        ushort8v o = {f32_bf16(v0.x), f32_bf16(v0.y), f32_bf16(v0.z), f32_bf16(v0.w),
                      f32_bf16(v1.x), f32_bf16(v1.y), f32_bf16(v1.z), f32_bf16(v1.w)};
        *(ushort8v*)(yrow + k * 8) = o;
      }
    }
  }
  __syncthreads();  // scr reads done; safe to refill Mz
  {
    int s = t >> 1, n0 = (t & 1) * 64;
    float wd = wdec[s];
    const ushort8v* bv = (const ushort8v*)(xBC + (rowbase + s) * 2304 + 2048 + n0);
#pragma unroll
    for (int i = 0; i < 8; ++i) {
      ushort8v bb = bv[i];
#pragma unroll
      for (int j = 0; j < 8; ++j) Mz[(n0 + i * 8 + j) * 136 + s] = f32_bf16(bf2f(bb[j]) * wd);
    }
  }
  __syncthreads();
  {
    floatx4 acc[2][4];
#pragma unroll
    for (int i = 0; i < 2; ++i)
#pragma unroll
      for (int j = 0; j < 4; ++j) acc[i][j] = (floatx4){0.f, 0.f, 0.f, 0.f};
#pragma unroll
    for (int k0 = 0; k0 < 128; k0 += 32) {
      int kk = k0 + hi * 8;
      bf16x8 a0 = *(const bf16x8*)(Mz + (q0 + fr) * 136 + kk);
      bf16x8 a1 = *(const bf16x8*)(Mz + (q0 + 16 + fr) * 136 + kk);
      bf16x8 bf_[4];
#pragma unroll
      for (int j = 0; j < 4; ++j) bf_[j] = *(const bf16x8*)(xdT + (j * 16 + fr) * 136 + kk);
#pragma unroll
      for (int j = 0; j < 4; ++j) {
        acc[0][j] = __builtin_amdgcn_mfma_f32_16x16x32_bf16(a0, bf_[j], acc[0][j], 0, 0, 0);
        acc[1][j] = __builtin_amdgcn_mfma_f32_16x16x32_bf16(a1, bf_[j], acc[1][j], 0, 0, 0);
      }
    }
    // states epilogue: acc -> LDS [64 p][132 n] f32 -> ushort8 stores.
    __syncthreads();  // all waves done reading Mz for states
    float* scr = (float*)Mz;
#pragma unroll
    for (int i = 0; i < 2; ++i)
#pragma unroll
      for (int j = 0; j < 4; ++j) {
        int p = j * 16 + fr;
        int n = q0 + i * 16 + hi * 4;
#pragma unroll
        for (int r = 0; r < 4; ++r) scr[p * 132 + n + r] = acc[i][j][r];
      }
    __syncthreads();
    {
      unsigned short* st = states + (long long)bx * 8192;
      int p = t >> 2, nh = (t & 3) * 32;
      unsigned short* strow = st + p * 128 + nh;
      const float* sp = scr + p * 132 + nh;
#pragma unroll
      for (int k = 0; k < 4; ++k) {
        float4 v0 = *(const float4*)(sp + k * 8);
        float4 v1 = *(const float4*)(sp + k * 8 + 4);
        ushort8v o = {f32_bf16(v0.x), f32_bf16(v0.y), f32_bf16(v0.z), f32_bf16(v0.w),
                      f32_bf16(v1.x), f32_bf16(v1.y), f32_bf16(v1.z), f32_bf16(v1.w)};
        *(ushort8v*)(strow + k * 8) = o;
      }
    }
  }
}

// ---------------------------------------------------------------------------
// Inter-chunk scan: 256 blocks (b,h,seg), ushort8 RMW, 8 elems/thread.
// ---------------------------------------------------------------------------
__global__ __launch_bounds__(256) void ssd_scan_k(const float* __restrict__ dA_cs,
                                                  unsigned short* __restrict__ states) {
  int seg = blockIdx.x & 3;
  int h = (blockIdx.x >> 2) & 31;
  int b = blockIdx.x >> 7;
  int t = threadIdx.x;
  int e0 = seg * 2048 + t * 8;
  float carry[8];
#pragma unroll
  for (int i = 0; i < 8; ++i) carry[i] = 0.f;
  for (int c = 0; c < 16; ++c) {
    long long base = ((long long)((b * 16 + c) * 32 + h)) * 8192;
    float dec = __expf(dA_cs[(((long long)((b * 32 + h) * 16 + c)) << 7) + 127]);
    ushort8v v = *(const ushort8v*)(states + base + e0);
    ushort8v o;
#pragma unroll
    for (int i = 0; i < 8; ++i) {
      float local = bf2f(v[i]);
      o[i] = f32_bf16(carry[i]);
      carry[i] = dec * carry[i] + local;
    }
    *(ushort8v*)(states + base + e0) = o;
  }
}

// ---------------------------------------------------------------------------
// Y_off + D-skip (MFMA). R8: acc routed through LDS [128][68] f32, then fully
// vectorized ushort8 read-modify-write of y (+ ushort8 x loads).
// ---------------------------------------------------------------------------
__global__ __launch_bounds__(256) void ssd_off_k(const unsigned short* __restrict__ xBC,
                                                 const float* __restrict__ dA_cs,
                                                 const unsigned short* __restrict__ states,
                                                 const float* __restrict__ Dvec,
                                                 unsigned short* __restrict__ y) {
  __shared__ float eA[128];
  __shared__ float scr[128 * 68];  // 34816 B
  const int bx = blockIdx.x;
  const int h = bx & 31, c = (bx >> 5) & 15, b = bx >> 9;
  const int t = threadIdx.x;
  const int w = t >> 6, lane = t & 63, fr = lane & 15, hi = lane >> 4;
  const long long rowbase = (long long)b * 2048 + c * 128;
  const long long abase = ((long long)((b * 32 + h) * 16 + c)) << 7;
  if (t < 128) eA[t] = __expf(dA_cs[abase + t]);
  __syncthreads();

  const unsigned short* st = states + (long long)bx * 8192;
  const int q0 = w << 5;
  floatx4 acc[2][4];
#pragma unroll
  for (int i = 0; i < 2; ++i)
#pragma unroll
    for (int j = 0; j < 4; ++j) acc[i][j] = (floatx4){0.f, 0.f, 0.f, 0.f};

#pragma unroll
  for (int k0 = 0; k0 < 128; k0 += 32) {
    int kk = k0 + hi * 8;
    bf16x8 a0 = *(const bf16x8*)(xBC + (rowbase + q0 + fr) * 2304 + 2176 + kk);
    bf16x8 a1 = *(const bf16x8*)(xBC + (rowbase + q0 + 16 + fr) * 2304 + 2176 + kk);
    bf16x8 bf_[4];
#pragma unroll
    for (int j = 0; j < 4; ++j) bf_[j] = *(const bf16x8*)(st + (j * 16 + fr) * 128 + kk);
#pragma unroll
    for (int j = 0; j < 4; ++j) {
      acc[0][j] = __builtin_amdgcn_mfma_f32_16x16x32_bf16(a0, bf_[j], acc[0][j], 0, 0, 0);
      acc[1][j] = __builtin_amdgcn_mfma_f32_16x16x32_bf16(a1, bf_[j], acc[1][j], 0, 0, 0);
    }
  }

#pragma unroll
  for (int i = 0; i < 2; ++i)
#pragma unroll
    for (int r = 0; r < 4; ++r) {
      int q = q0 + i * 16 + hi * 4 + r;
#pragma unroll
      for (int j = 0; j < 4; ++j) scr[q * 68 + j * 16 + fr] = acc[i][j][r];
    }
  __syncthreads();
  {
    float Dh = Dvec[h];
    int row = t >> 1, colh = (t & 1) * 32;
    float e = eA[row];
    const unsigned short* xrow = xBC + (rowbase + row) * 2304 + h * 64 + colh;
    unsigned short* yrow = y + (rowbase + row) * 2048 + h * 64 + colh;
    const float* sp = scr + row * 68 + colh;
#pragma unroll
    for (int k = 0; k < 4; ++k) {
      ushort8v yv = *(const ushort8v*)(yrow + k * 8);
      ushort8v xv = *(const ushort8v*)(xrow + k * 8);
      float4 a0 = *(const float4*)(sp + k * 8);
      float4 a1 = *(const float4*)(sp + k * 8 + 4);
      float av[8] = {a0.x, a0.y, a0.z, a0.w, a1.x, a1.y, a1.z, a1.w};
      ushort8v o;
#pragma unroll
      for (int e2 = 0; e2 < 8; ++e2)
        o[e2] = f32_bf16(bf2f(yv[e2]) + e * av[e2] + Dh * bf2f(xv[e2]));
      *(ushort8v*)(yrow + k * 8) = o;
    }
  }
}

// ---------------------------------------------------------------------------
extern "C" void kernel_launch(void* const* d_in, const int* in_sizes, int n_in, void* d_out,
                              int out_size, void* d_ws, size_t ws_size, hipStream_t stream) {
  const float* hs = (const float*)d_in[0];
  const float* w_ln1 = (const float*)d_in[1];
  const float* w_in = (const float*)d_in[2];
  const float* w_conv = (const float*)d_in[3];
  const float* b_conv = (const float*)d_in[4];
  const float* dt_bias = (const float*)d_in[5];
  const float* A_log = (const float*)d_in[6];
  const float* Dvec = (const float*)d_in[7];
  const float* w_mnorm = (const float*)d_in[8];
  const float* w_out = (const float*)d_in[9];
  const float* w_ln2 = (const float*)d_in[10];
  const float* w_gate = (const float*)d_in[11];
  const float* w_up = (const float*)d_in[12];
  const float* w_down = (const float*)d_in[13];
  float* out = (float*)d_out;
  const int M = 4096;

  char* ws = (char*)d_ws;
  const size_t R0 = 0;
  const size_t R1 = 33554432;
  const size_t R1b = R1 + 33554432;
  const size_t R2 = 71303168;
  const size_t R3 = 90177536;
  const size_t R4 = 107544576;
  const size_t W0 = 108068864;
  const size_t NEED = 133234688;

  if (ws_size < NEED) {
    hipLaunchKernelGGL(zero_out_k, dim3((out_size + 255) / 256), dim3(256), 0, stream, out,
                       (long long)out_size);
    return;
  }

  unsigned short* z = (unsigned short*)(ws + R0);
  unsigned short* act = (unsigned short*)(ws + R0);
  float* oproj_parts = (float*)(ws + R0);
  unsigned short* xraw = (unsigned short*)(ws + R1);
  unsigned short* states = (unsigned short*)(ws + R1);
  unsigned short* ybuf = (unsigned short*)(ws + R1 + 16777216);
  unsigned short* upo = (unsigned short*)(ws + R1);
  float* down_parts = (float*)(ws + R1);
  unsigned short* wbf_out = (unsigned short*)(ws + R1b);
  unsigned short* xBC = (unsigned short*)(ws + R2);
  unsigned short* ygn = (unsigned short*)(ws + R2);
  unsigned short* h2 = (unsigned short*)(ws + R2);
  unsigned short* hnorm = (unsigned short*)(ws + R3);
  unsigned short* wbf_in = (unsigned short*)(ws + R3 + 8388608);
  float* dt_s = (float*)(ws + R3);
  float* dA_cs = (float*)(ws + R3 + 524288);
  unsigned short* Gbuf = (unsigned short*)(ws + R3 + 1048576);
  float* mh = (float*)(ws + R3);
  float* dtraw = (float*)(ws + R4);
  unsigned short* wbf_gate = (unsigned short*)(ws + W0);
  unsigned short* wbf_up = (unsigned short*)(ws + W0 + 8388608);
  unsigned short* wbf_down = (unsigned short*)(ws + W0 + 16777216);

  // s1: rmsnorm(ln1) -> hnorm bf16
  hipLaunchKernelGGL(rmsnorm1024_bf16_k, dim3(M), dim3(256), 0, stream, hs, w_ln1, hnorm, 1e-6f);
  // s2: ALL weight conversions in one launch (incl. w_out)
  hipLaunchKernelGGL(wconv_all_k, dim3(18720), dim3(256), 0, stream, w_in, w_gate, w_up, w_down,
                     w_out, wbf_in, wbf_gate, wbf_up, wbf_down, wbf_out);
  // s3: in_proj -> z bf16 / xraw bf16 / dtraw fp32 (BN=128: 2+ blocks/CU)
  hipLaunchKernelGGL((gemm128<1, 128>), dim3(16, 32, 1), dim3(256), 0, stream, hnorm, wbf_in,
                     (void*)z, (const unsigned short*)nullptr, 1024, 1024, 1024, 2048, 0LL, 0LL,
                     0LL);
  hipLaunchKernelGGL((gemm128<1, 128>), dim3(18, 32, 1), dim3(256), 0, stream, hnorm,
                     wbf_in + 2048 * 1024, (void*)xraw, (const unsigned short*)nullptr, 1024, 1024,
                     1024, 2304, 0LL, 0LL, 0LL);
  hipLaunchKernelGGL((gemm_small_nt<1>), dim3(1, 64, 1), dim3(256), 0, stream, hnorm,
                     wbf_in + 4352 * 1024, dtraw, M, 32, 1024, 1024, 1024, 32);
  // s4: conv + silu -> xBC bf16 (flat balanced grid)
  hipLaunchKernelGGL(conv_silu_k, dim3(4608), dim3(256), 0, stream, xraw, w_conv, b_conv, xBC);
  // s5+s6 fused: dt softplus + dA cumsum
  hipLaunchKernelGGL(dA_cumsum_k, dim3(1024), dim3(128), 0, stream, dtraw, dt_bias, A_log, dt_s,
                     dA_cs);
  // s7: G = C @ B^T per chunk, stored bf16
  hipLaunchKernelGGL((gemm128<1, 128>), dim3(1, 1, 32), dim3(256), 0, stream, xBC + 2176,
                     xBC + 2048, (void*)Gbuf, (const unsigned short*)nullptr, 128, 2304, 2304, 128,
                     294912LL, 294912LL, 16384LL);
  // s8: Y_diag + local states (MFMA, vectorized epilogues)
  hipLaunchKernelGGL(ssd_diag_states_k, dim3(1024), dim3(256), 0, stream, xBC, dt_s, dA_cs, Gbuf,
                     ybuf, states);
  // s9: inter-chunk scan (ushort8 RMW)
  hipLaunchKernelGGL(ssd_scan_k, dim3(256), dim3(256), 0, stream, dA_cs, states);
  // s10: Y_off + D-skip (MFMA, vectorized RMW)
  hipLaunchKernelGGL(ssd_off_k, dim3(1024), dim3(256), 0, stream, xBC, dA_cs, states, Dvec, ybuf);
  // s11: gated rmsnorm -> ygn bf16
  hipLaunchKernelGGL(gated_rmsnorm2048_k, dim3(M), dim3(256), 0, stream, ybuf, z, w_mnorm, ygn,
                     1e-5f);
  // s12: out_proj, BN=128 split-K=2 -> 512 blocks
  hipLaunchKernelGGL((gemm128<0, 128>), dim3(8, 32, 2), dim3(256), 0, stream, ygn, wbf_out,
                     (void*)oproj_parts, (const unsigned short*)nullptr, 1024, 2048, 2048, 1024,
                     1024LL, 1024LL, 4194304LL);
  // s13: mh = hs + sum(partials); h2 = rmsnorm(mh, ln2)  [fused]
  hipLaunchKernelGGL(add_rmsnorm_k, dim3(M), dim3(256), 0, stream, hs, oproj_parts, 4194304LL, 2,
                     w_ln2, mh, h2, 1e-6f);
  // s15: up -> upo bf16 (BN=256, 512 blocks)
  hipLaunchKernelGGL((gemm128<1, 256>), dim3(16, 32, 1), dim3(256), 0, stream, h2, wbf_up,
                     (void*)upo, (const unsigned short*)nullptr, 1024, 1024, 1024, 4096, 0LL, 0LL,
                     0LL);
  // s16: gate with fused swiglu -> act bf16 (BN=256, 512 blocks)
  hipLaunchKernelGGL((gemm128<2, 256>), dim3(16, 32, 1), dim3(256), 0, stream, h2, wbf_gate,
                     (void*)act, upo, 1024, 1024, 1024, 4096, 0LL, 0LL, 0LL);
  // s17: down, BN=128 split-K=2 -> 512 blocks
  hipLaunchKernelGGL((gemm128<0, 128>), dim3(8, 32, 2), dim3(256), 0, stream, act, wbf_down,
                     (void*)down_parts, (const unsigned short*)nullptr, 2048, 4096, 4096, 1024,
                     2048LL, 2048LL, 4194304LL);
  // s18: out = mh + sum(partials)
  hipLaunchKernelGGL(addn_f32_k, dim3(4096), dim3(256), 0, stream, mh, down_parts, 4194304LL, 2,
                     out, 1048576LL);
}

// Round 10
// 511.897 us; speedup vs baseline: 1.0224x; 1.0224x over previous
//
#include <hip/hip_runtime.h>

#define DEV static __device__ __forceinline__

typedef short bf16x8 __attribute__((ext_vector_type(8)));
typedef float floatx4 __attribute__((ext_vector_type(4)));
typedef unsigned short ushort4v __attribute__((ext_vector_type(4)));
typedef unsigned short ushort8v __attribute__((ext_vector_type(8)));

DEV unsigned short f32_bf16(float f) {
  unsigned int u = __builtin_bit_cast(unsigned int, f);
  u = u + 0x7fffu + ((u >> 16) & 1u);
  return (unsigned short)(u >> 16);
}
DEV float bf2f(unsigned short u) {
  unsigned int v = ((unsigned int)u) << 16;
  return __builtin_bit_cast(float, v);
}
DEV float sigmoidf_(float x) { return 1.0f / (1.0f + __expf(-x)); }
DEV float siluf_(float x) { return x * sigmoidf_(x); }

#define GLD_LDS16(g, l)                                                              \
  __builtin_amdgcn_global_load_lds((const __attribute__((address_space(1))) void*)(g), \
                                   (__attribute__((address_space(3))) void*)(l), 16, 0, 0)

// ---------------------------------------------------------------------------
// Pipelined MFMA GEMM: C[M,N] = A[M,K] @ B[N,K]^T, bf16 in, 128xBN block tile.
// BN per dispatch so grid >= 2 blocks/CU (R7-verified). DOUBLE-buffered LDS,
// 2-barrier loop, counted vmcnt. Epilogue (MODE 1/2): f32 acc -> LDS
// [32][BN+4] four 32-row passes -> ushort8 stores. MODE 0: fp32 store.
// ---------------------------------------------------------------------------
template <int MODE, int BN>
__global__ __launch_bounds__(256) void gemm128(
    const unsigned short* __restrict__ A, const unsigned short* __restrict__ B,
    void* __restrict__ Cv, const unsigned short* __restrict__ other,
    int K, int lda, int ldb, int ldc, long long bsA, long long bsB, long long bsC) {
  constexpr int NBG = BN / 64;           // B gload_lds per wave per stage (2|4)
  constexpr int NJ = BN / 32;            // j-fragments per wave (4|8)
  constexpr int BUFSZ = 4096 + BN * 32;  // ushorts per buffer (A 128x32 + B BNx32)
  __shared__ unsigned short S[2 * BUFSZ];
  A += (long long)blockIdx.z * bsA;
  B += (long long)blockIdx.z * bsB;
  const long long coff = (long long)blockIdx.z * bsC;
  const int tid = threadIdx.x;
  const int w = tid >> 6, lane = tid & 63;

  // GM=4 supertile swizzle: consecutive blocks walk M within a 4-row group.
  const int nbx = gridDim.x, nby = gridDim.y;
  const int GM = 4;
  int bid = blockIdx.y * nbx + blockIdx.x;
  int gid = bid / (GM * nbx);
  int rem = bid - gid * (GM * nbx);
  int gsz = min(GM, nby - gid * GM);
  int mtile = gid * GM + rem % gsz;
  int ntile = rem / gsz;
  const int m0 = mtile << 7, n0 = ntile * BN;

  const int srow = lane >> 2;
  const int schunk = ((lane & 3) ^ (srow & 3)) * 8;  // pre-swizzled global src
  const unsigned short* ag0 = A + (long long)(m0 + w * 32 + srow) * lda + schunk;
  const unsigned short* ag1 = ag0 + (long long)16 * lda;
  const unsigned short* bgp[NBG];
#pragma unroll
  for (int ii = 0; ii < NBG; ++ii)
    bgp[ii] = B + (long long)(n0 + w * (BN / 4) + srow + 16 * ii) * ldb + schunk;

  auto STAGE = [&](int buf, int k0) {
    unsigned short* as_ = S + buf * BUFSZ;
    unsigned short* bs_ = as_ + 4096;
    GLD_LDS16(ag0 + k0, as_ + w * 1024 + lane * 8);
    GLD_LDS16(ag1 + k0, as_ + w * 1024 + lane * 8 + 512);
#pragma unroll
    for (int ii = 0; ii < NBG; ++ii)
      GLD_LDS16(bgp[ii] + k0, bs_ + w * (NBG * 512) + ii * 512 + lane * 8);
  };

  const int wr = (w >> 1) << 6;
  const int wc = (w & 1) * (BN / 2);
  const int fr = lane & 15;
  const int slot = (((lane >> 4) ^ (fr & 3))) << 3;
  const int r0 = (lane >> 4) << 2;

  floatx4 acc[4][NJ];
#pragma unroll
  for (int i = 0; i < 4; ++i)
#pragma unroll
    for (int j = 0; j < NJ; ++j) acc[i][j] = (floatx4){0.f, 0.f, 0.f, 0.f};

  const int nsteps = K >> 5;
  STAGE(0, 0);
  if (nsteps > 1) STAGE(1, 32);

  for (int t = 0; t < nsteps; ++t) {
    if (t < nsteps - 1) {
      if constexpr (NBG == 2) {
        asm volatile("s_waitcnt vmcnt(4)" ::: "memory");
      } else {
        asm volatile("s_waitcnt vmcnt(6)" ::: "memory");
      }
    } else {
      asm volatile("s_waitcnt vmcnt(0)" ::: "memory");
    }
    __builtin_amdgcn_s_barrier();
    __builtin_amdgcn_sched_barrier(0);
    const unsigned short* Ab = S + (t & 1) * BUFSZ;
    const unsigned short* Bb = Ab + 4096;
    bf16x8 af[4], bf_[NJ];
#pragma unroll
    for (int i = 0; i < 4; ++i)
      af[i] = *(const bf16x8*)(Ab + (wr + i * 16 + fr) * 32 + slot);
#pragma unroll
    for (int j = 0; j < NJ; ++j)
      bf_[j] = *(const bf16x8*)(Bb + (wc + j * 16 + fr) * 32 + slot);
#pragma unroll
    for (int i = 0; i < 4; ++i)
#pragma unroll
      for (int j = 0; j < NJ; ++j)
        acc[i][j] = __builtin_amdgcn_mfma_f32_16x16x32_bf16(af[i], bf_[j], acc[i][j], 0, 0, 0);
    __builtin_amdgcn_sched_barrier(0);
    __builtin_amdgcn_s_barrier();
    if (t + 2 < nsteps) STAGE(t & 1, (t + 2) * 32);
  }

  if constexpr (MODE == 0) {
#pragma unroll
    for (int i = 0; i < 4; ++i) {
#pragma unroll
      for (int j = 0; j < NJ; ++j) {
        long long base = (long long)(m0 + wr + i * 16 + r0) * ldc + (n0 + wc + j * 16 + fr);
#pragma unroll
        for (int r = 0; r < 4; ++r) {
          ((float*)Cv)[coff + base + (long long)r * ldc] = acc[i][j][r];
        }
      }
    }
  } else {
    constexpr int PAD = BN + 4;
    float* scr = (float*)S;
    const int row_l = tid >> 3;      // 0..31
    const int col0 = (tid & 7) * 8;  // 0..56 step 8
    __syncthreads();
#pragma unroll
    for (int pass = 0; pass < 4; ++pass) {
      if ((w >> 1) == (pass >> 1)) {
#pragma unroll
        for (int ii = 0; ii < 2; ++ii) {
          int i = (pass & 1) * 2 + ii;
          int rl = i * 16 + r0 - (pass & 1) * 32;  // 0..31
#pragma unroll
          for (int j = 0; j < NJ; ++j) {
            int col = wc + j * 16 + fr;
#pragma unroll
            for (int r = 0; r < 4; ++r) scr[(rl + r) * PAD + col] = acc[i][j][r];
          }
        }
      }
      __syncthreads();
      long long grow = m0 + pass * 32 + row_l;
      long long gbase = coff + grow * ldc + n0;
      const float* srow_p = scr + row_l * PAD;
#pragma unroll
      for (int k = 0; k < BN / 64; ++k) {
        int col = col0 + k * 64;
        float v[8];
        *(float4*)&v[0] = *(const float4*)(srow_p + col);
        *(float4*)&v[4] = *(const float4*)(srow_p + col + 4);
        ushort8v o;
        if constexpr (MODE == 2) {
          ushort8v uo = *(const ushort8v*)(other + gbase + col);
#pragma unroll
          for (int e = 0; e < 8; ++e) o[e] = f32_bf16(siluf_(v[e]) * bf2f(uo[e]));
        } else {
#pragma unroll
          for (int e = 0; e < 8; ++e) o[e] = f32_bf16(v[e]);
        }
        *(ushort8v*)((unsigned short*)Cv + gbase + col) = o;
      }
      __syncthreads();
    }
  }
}

// ---------------------------------------------------------------------------
// Fused gate+up swiglu dual GEMM, 128x128 tile (BN=128 path of the verified
// template). act = bf16(silu(A@Bg^T) * (A@Bu^T)). One A staging feeds two
// B-panel MFMA streams: 32 MFMA per 6 global_load_lds (2x intensity), and
// the upo intermediate round-trip disappears. __launch_bounds__(256,2) caps
// the unified VGPR+AGPR allocation at 256 (R2's failure was 264 regs -> 1
// wave/SIMD; acc=128 AGPR + ~90 VGPR fits 2 waves/SIMD = 2 blocks/CU).
// LDS: 2 buf x (A+Bg+Bu = 24KB) = 48KB. Same 2-barrier counted-vmcnt loop.
// ---------------------------------------------------------------------------
__global__ __launch_bounds__(256, 2) void gemm128_dual(
    const unsigned short* __restrict__ A, const unsigned short* __restrict__ Bg,
    const unsigned short* __restrict__ Bu, unsigned short* __restrict__ C,
    int K, int lda, int ldb, int ldc) {
  __shared__ unsigned short S[2 * 12288];
  const int tid = threadIdx.x;
  const int w = tid >> 6, lane = tid & 63;
  const int nbx = gridDim.x, nby = gridDim.y;
  const int GM = 4;
  int bid = blockIdx.y * nbx + blockIdx.x;
  int gid = bid / (GM * nbx);
  int rem = bid - gid * (GM * nbx);
  int gsz = min(GM, nby - gid * GM);
  int mtile = gid * GM + rem % gsz;
  int ntile = rem / gsz;
  const int m0 = mtile << 7, n0 = ntile << 7;

  const int srow = lane >> 2;
  const int schunk = ((lane & 3) ^ (srow & 3)) * 8;
  const unsigned short* ag0 = A + (long long)(m0 + w * 32 + srow) * lda + schunk;
  const unsigned short* ag1 = ag0 + (long long)16 * lda;
  const unsigned short* gg0 = Bg + (long long)(n0 + w * 32 + srow) * ldb + schunk;
  const unsigned short* gg1 = gg0 + (long long)16 * ldb;
  const unsigned short* ug0 = Bu + (long long)(n0 + w * 32 + srow) * ldb + schunk;
  const unsigned short* ug1 = ug0 + (long long)16 * ldb;

  auto STAGE = [&](int buf, int k0) {
    unsigned short* as_ = S + buf * 12288;
    unsigned short* gs_ = as_ + 4096;
    unsigned short* us_ = as_ + 8192;
    GLD_LDS16(ag0 + k0, as_ + w * 1024 + lane * 8);
    GLD_LDS16(ag1 + k0, as_ + w * 1024 + lane * 8 + 512);
    GLD_LDS16(gg0 + k0, gs_ + w * 1024 + lane * 8);
    GLD_LDS16(gg1 + k0, gs_ + w * 1024 + lane * 8 + 512);
    GLD_LDS16(ug0 + k0, us_ + w * 1024 + lane * 8);
    GLD_LDS16(ug1 + k0, us_ + w * 1024 + lane * 8 + 512);
  };

  const int wr = (w >> 1) << 6;
  const int wc = (w & 1) << 6;
  const int fr = lane & 15;
  const int slot = (((lane >> 4) ^ (fr & 3))) << 3;
  const int r0 = (lane >> 4) << 2;

  floatx4 accg[4][4], accu[4][4];
#pragma unroll
  for (int i = 0; i < 4; ++i)
#pragma unroll
    for (int j = 0; j < 4; ++j) {
      accg[i][j] = (floatx4){0.f, 0.f, 0.f, 0.f};
      accu[i][j] = (floatx4){0.f, 0.f, 0.f, 0.f};
    }

  const int nsteps = K >> 5;
  STAGE(0, 0);
  if (nsteps > 1) STAGE(1, 32);

  for (int t = 0; t < nsteps; ++t) {
    if (t < nsteps - 1) {
      asm volatile("s_waitcnt vmcnt(6)" ::: "memory");
    } else {
      asm volatile("s_waitcnt vmcnt(0)" ::: "memory");
    }
    __builtin_amdgcn_s_barrier();
    __builtin_amdgcn_sched_barrier(0);
    const unsigned short* Ab = S + (t & 1) * 12288;
    const unsigned short* Gb = Ab + 4096;
    const unsigned short* Ub = Ab + 8192;
    bf16x8 af[4], gf[4], uf[4];
#pragma unroll
    for (int i = 0; i < 4; ++i)
      af[i] = *(const bf16x8*)(Ab + (wr + i * 16 + fr) * 32 + slot);
#pragma unroll
    for (int j = 0; j < 4; ++j) {
      gf[j] = *(const bf16x8*)(Gb + (wc + j * 16 + fr) * 32 + slot);
      uf[j] = *(const bf16x8*)(Ub + (wc + j * 16 + fr) * 32 + slot);
    }
#pragma unroll
    for (int i = 0; i < 4; ++i)
#pragma unroll
      for (int j = 0; j < 4; ++j) {
        accg[i][j] = __builtin_amdgcn_mfma_f32_16x16x32_bf16(af[i], gf[j], accg[i][j], 0, 0, 0);
        accu[i][j] = __builtin_amdgcn_mfma_f32_16x16x32_bf16(af[i], uf[j], accu[i][j], 0, 0, 0);
      }
    __builtin_amdgcn_sched_barrier(0);
    __builtin_amdgcn_s_barrier();
    if (t + 2 < nsteps) STAGE(t & 1, (t + 2) * 32);
  }

  // In-register swiglu, then the verified 4-pass LDS-transpose epilogue.
#pragma unroll
  for (int i = 0; i < 4; ++i)
#pragma unroll
    for (int j = 0; j < 4; ++j)
#pragma unroll
      for (int r = 0; r < 4; ++r) accg[i][j][r] = siluf_(accg[i][j][r]) * accu[i][j][r];

  constexpr int PAD = 132;
  float* scr = (float*)S;
  const int row_l = tid >> 3;
  const int col0 = (tid & 7) * 8;
  __syncthreads();
#pragma unroll
  for (int pass = 0; pass < 4; ++pass) {
    if ((w >> 1) == (pass >> 1)) {
#pragma unroll
      for (int ii = 0; ii < 2; ++ii) {
        int i = (pass & 1) * 2 + ii;
        int rl = i * 16 + r0 - (pass & 1) * 32;
#pragma unroll
        for (int j = 0; j < 4; ++j) {
          int col = wc + j * 16 + fr;
#pragma unroll
          for (int r = 0; r < 4; ++r) scr[(rl + r) * PAD + col] = accg[i][j][r];
        }
      }
    }
    __syncthreads();
    long long grow = m0 + pass * 32 + row_l;
    long long gbase = grow * (long long)ldc + n0;
    const float* srow_p = scr + row_l * PAD;
#pragma unroll
    for (int k = 0; k < 2; ++k) {
      int col = col0 + k * 64;
      float v[8];
      *(float4*)&v[0] = *(const float4*)(srow_p + col);
      *(float4*)&v[4] = *(const float4*)(srow_p + col + 4);
      ushort8v o;
#pragma unroll
      for (int e = 0; e < 8; ++e) o[e] = f32_bf16(v[e]);
      *(ushort8v*)(C + gbase + col) = o;
    }
    __syncthreads();
  }
}

// ---------------------------------------------------------------------------
// small GEMM (direct-from-global), used only for the N=32 dt projection.
// ---------------------------------------------------------------------------
template <int WM>
__global__ __launch_bounds__(256) void gemm_small_nt(
    const unsigned short* __restrict__ A, const unsigned short* __restrict__ B,
    float* __restrict__ C, int M, int N, int K, int lda, int ldb, int ldc) {
  const int w = threadIdx.x >> 6;
  const int lane = threadIdx.x & 63;
  const int lm = lane & 15;
  const int ko = (lane >> 4) << 3;
  const int bn0 = blockIdx.x << 6;
  const int m_base = blockIdx.y * (WM * 64) + w * (WM * 16);

  const unsigned short* arow[WM];
#pragma unroll
  for (int i = 0; i < WM; ++i) arow[i] = A + (long long)(m_base + i * 16 + lm) * lda + ko;
  int nv = (N - bn0) >> 4;
  nv = nv > 4 ? 4 : nv;
  const unsigned short* brow[4];
#pragma unroll
  for (int j = 0; j < 4; ++j) {
    int nr = bn0 + j * 16 + lm;
    brow[j] = B + (long long)(j < nv ? nr : 0) * ldb + ko;
  }
  floatx4 acc[WM][4];
#pragma unroll
  for (int i = 0; i < WM; ++i)
#pragma unroll
    for (int j = 0; j < 4; ++j) acc[i][j] = (floatx4){0.f, 0.f, 0.f, 0.f};
  for (int k0 = 0; k0 < K; k0 += 32) {
    bf16x8 a[WM];
#pragma unroll
    for (int i = 0; i < WM; ++i) a[i] = *(const bf16x8*)(arow[i] + k0);
#pragma unroll
    for (int j = 0; j < 4; ++j) {
      if (j < nv) {
        bf16x8 b = *(const bf16x8*)(brow[j] + k0);
#pragma unroll
        for (int i = 0; i < WM; ++i)
          acc[i][j] = __builtin_amdgcn_mfma_f32_16x16x32_bf16(a[i], b, acc[i][j], 0, 0, 0);
      }
    }
  }
  const int r0 = (lane >> 4) << 2;
#pragma unroll
  for (int i = 0; i < WM; ++i)
#pragma unroll
    for (int j = 0; j < 4; ++j)
      if (j < nv) {
        int col = bn0 + j * 16 + lm;
        long long base = (long long)(m_base + i * 16 + r0) * ldc + col;
#pragma unroll
        for (int r = 0; r < 4; ++r) C[base + (long long)r * ldc] = acc[i][j][r];
      }
}

// ---------------------------------------------------------------------------
// All weight conversions fused into one kernel (5 ranges, float4 units).
// ---------------------------------------------------------------------------
__global__ __launch_bounds__(256) void wconv_all_k(
    const float* __restrict__ w_in, const float* __restrict__ w_gate,
    const float* __restrict__ w_up, const float* __restrict__ w_down,
    const float* __restrict__ w_out, unsigned short* __restrict__ d_in_,
    unsigned short* __restrict__ d_gate, unsigned short* __restrict__ d_up,
    unsigned short* __restrict__ d_down, unsigned short* __restrict__ d_out_) {
  long long j = (long long)blockIdx.x * 256 + threadIdx.x;
  const float* src;
  unsigned short* dst;
  if (j < 1122304) {
    src = w_in; dst = d_in_;
  } else if ((j -= 1122304) < 1048576) {
    src = w_gate; dst = d_gate;
  } else if ((j -= 1048576) < 1048576) {
    src = w_up; dst = d_up;
  } else if ((j -= 1048576) < 1048576) {
    src = w_down; dst = d_down;
  } else if ((j -= 1048576) < 524288) {
    src = w_out; dst = d_out_;
  } else {
    return;
  }
  float4 v = ((const float4*)src)[j];
  ushort4v o = {f32_bf16(v.x), f32_bf16(v.y), f32_bf16(v.z), f32_bf16(v.w)};
  ((ushort4v*)dst)[j] = o;
}

__global__ __launch_bounds__(256) void zero_out_k(float* __restrict__ o, long long n) {
  long long i = (long long)blockIdx.x * 256 + threadIdx.x;
  if (i < n) o[i] = 0.f;
}

// ---------------------------------------------------------------------------
__global__ __launch_bounds__(256) void rmsnorm1024_bf16_k(const float* __restrict__ x,
                                                          const float* __restrict__ w,
                                                          unsigned short* __restrict__ out,
                                                          float eps) {
  long long row = blockIdx.x;
  int t = threadIdx.x;
  float4 v = ((const float4*)(x + row * 1024))[t];
  float ss = v.x * v.x + v.y * v.y + v.z * v.z + v.w * v.w;
  __shared__ float red[4];
#pragma unroll
  for (int o = 32; o > 0; o >>= 1) ss += __shfl_down(ss, o, 64);
  if ((t & 63) == 0) red[t >> 6] = ss;
  __syncthreads();
  float tot = red[0] + red[1] + red[2] + red[3];
  float sc = rsqrtf(tot * (1.0f / 1024.0f) + eps);
  float4 wv = ((const float4*)w)[t];
  ushort4v o = {f32_bf16(v.x * sc * wv.x), f32_bf16(v.y * sc * wv.y),
                f32_bf16(v.z * sc * wv.z), f32_bf16(v.w * sc * wv.w)};
  ((ushort4v*)(out + row * 1024))[t] = o;
}

// ---------------------------------------------------------------------------
// Fused: mh = hs + sum_{p<np} parts[p]; h2 = bf16(rmsnorm(mh) * w). 1024 cols.
// ---------------------------------------------------------------------------
__global__ __launch_bounds__(256) void add_rmsnorm_k(const float* __restrict__ hs,
                                                     const float* __restrict__ parts,
                                                     long long pstride, int np,
                                                     const float* __restrict__ w,
                                                     float* __restrict__ mh,
                                                     unsigned short* __restrict__ h2, float eps) {
  long long row = blockIdx.x;
  int t = threadIdx.x;
  float4 v = ((const float4*)(hs + row * 1024))[t];
  for (int p = 0; p < np; ++p) {
    float4 u = ((const float4*)(parts + p * pstride + row * 1024))[t];
    v.x += u.x;
    v.y += u.y;
    v.z += u.z;
    v.w += u.w;
  }
  ((float4*)(mh + row * 1024))[t] = v;
  float ss = v.x * v.x + v.y * v.y + v.z * v.z + v.w * v.w;
  __shared__ float red[4];
#pragma unroll
  for (int o = 32; o > 0; o >>= 1) ss += __shfl_down(ss, o, 64);
  if ((t & 63) == 0) red[t >> 6] = ss;
  __syncthreads();
  float tot = red[0] + red[1] + red[2] + red[3];
  float sc = rsqrtf(tot * (1.0f / 1024.0f) + eps);
  float4 wv = ((const float4*)w)[t];
  ushort4v o = {f32_bf16(v.x * sc * wv.x), f32_bf16(v.y * sc * wv.y),
                f32_bf16(v.z * sc * wv.z), f32_bf16(v.w * sc * wv.w)};
  ((ushort4v*)(h2 + row * 1024))[t] = o;
}

// ---------------------------------------------------------------------------
__global__ __launch_bounds__(256) void addn_f32_k(const float* __restrict__ a,
                                                  const float* __restrict__ parts,
                                                  long long pstride, int np,
                                                  float* __restrict__ o, long long n4) {
  long long i = (long long)blockIdx.x * 256 + threadIdx.x;
  if (i < n4) {
    float4 x = ((const float4*)a)[i];
    for (int p = 0; p < np; ++p) {
      float4 u = ((const float4*)(parts + p * pstride))[i];
      x.x += u.x;
      x.y += u.y;
      x.z += u.z;
      x.w += u.w;
    }
    ((float4*)o)[i] = x;
  }
}

// ---------------------------------------------------------------------------
__global__ __launch_bounds__(256) void gated_rmsnorm2048_k(const unsigned short* __restrict__ y,
                                                           const unsigned short* __restrict__ z,
                                                           const float* __restrict__ w,
                                                           unsigned short* __restrict__ out,
                                                           float eps) {
  long long row = blockIdx.x;
  int t = threadIdx.x;
  ushort8v yv = ((const ushort8v*)(y + row * 2048))[t];
  ushort8v zv = ((const ushort8v*)(z + row * 2048))[t];
  float g[8];
  float ss = 0.f;
#pragma unroll
  for (int j = 0; j < 8; ++j) {
    g[j] = bf2f(yv[j]) * siluf_(bf2f(zv[j]));
    ss += g[j] * g[j];
  }
  __shared__ float red[4];
#pragma unroll
  for (int o = 32; o > 0; o >>= 1) ss += __shfl_down(ss, o, 64);
  if ((t & 63) == 0) red[t >> 6] = ss;
  __syncthreads();
  float tot = red[0] + red[1] + red[2] + red[3];
  float sc = rsqrtf(tot * (1.0f / 2048.0f) + eps);
  float ww[8];
  *(float4*)&ww[0] = ((const float4*)w)[2 * t];
  *(float4*)&ww[4] = ((const float4*)w)[2 * t + 1];
  ushort8v o;
#pragma unroll
  for (int j = 0; j < 8; ++j) o[j] = f32_bf16(g[j] * sc * ww[j]);
  ((ushort8v*)(out + row * 2048))[t] = o;
}

// ---------------------------------------------------------------------------
// conv + silu: flat (m, cb) grid, 1 vec8 work item per thread.
// ---------------------------------------------------------------------------
__global__ __launch_bounds__(256) void conv_silu_k(const unsigned short* __restrict__ xraw,
                                                   const float* __restrict__ wconv,
                                                   const float* __restrict__ bconv,
                                                   unsigned short* __restrict__ xBC) {
  long long f = (long long)blockIdx.x * 256 + threadIdx.x;
  if (f >= 4096LL * 288) return;
  int m = (int)(f / 288);
  int cb = (int)(f - (long long)m * 288);
  int l = m & 2047;
  int ch0 = cb << 3;
  float acc[8];
  float4 bc0 = ((const float4*)bconv)[cb * 2];
  float4 bc1 = ((const float4*)bconv)[cb * 2 + 1];
  acc[0] = bc0.x; acc[1] = bc0.y; acc[2] = bc0.z; acc[3] = bc0.w;
  acc[4] = bc1.x; acc[5] = bc1.y; acc[6] = bc1.z; acc[7] = bc1.w;
  float4 wv[8];
#pragma unroll
  for (int j = 0; j < 8; ++j) wv[j] = ((const float4*)wconv)[ch0 + j];
#pragma unroll
  for (int k = 0; k < 4; ++k) {
    int lk = l + k - 3;
    if (lk >= 0) {
      ushort8v xv = *(const ushort8v*)(xraw + (long long)(m + k - 3) * 2304 + ch0);
      acc[0] += bf2f(xv[0]) * ((const float*)&wv[0])[k];
      acc[1] += bf2f(xv[1]) * ((const float*)&wv[1])[k];
      acc[2] += bf2f(xv[2]) * ((const float*)&wv[2])[k];
      acc[3] += bf2f(xv[3]) * ((const float*)&wv[3])[k];
      acc[4] += bf2f(xv[4]) * ((const float*)&wv[4])[k];
      acc[5] += bf2f(xv[5]) * ((const float*)&wv[5])[k];
      acc[6] += bf2f(xv[6]) * ((const float*)&wv[6])[k];
      acc[7] += bf2f(xv[7]) * ((const float*)&wv[7])[k];
    }
  }
  ushort8v o;
#pragma unroll
  for (int j = 0; j < 8; ++j) o[j] = f32_bf16(siluf_(acc[j]));
  *(ushort8v*)(xBC + (long long)m * 2304 + ch0) = o;
}

// ---------------------------------------------------------------------------
// Fused dt softplus + dA cumsum.
// ---------------------------------------------------------------------------
__global__ __launch_bounds__(128) void dA_cumsum_k(const float* __restrict__ dtraw,
                                                   const float* __restrict__ dt_bias,
                                                   const float* __restrict__ A_log,
                                                   float* __restrict__ dt_s,
                                                   float* __restrict__ dA_cs) {
  int bi = blockIdx.x;
  int c = bi & 15, h = (bi >> 4) & 31, b = bi >> 9;
  int q = threadIdx.x;
  long long idx = ((long long)(b * 2048 + c * 128 + q)) * 32 + h;
  float xv = dtraw[idx] + dt_bias[h];
  float sp = xv > 20.f ? xv : log1pf(expf(xv));
  dt_s[idx] = sp;
  float A = -expf(A_log[h]);
  float v = sp * A;
  __shared__ float sbuf[128];
  sbuf[q] = v;
  __syncthreads();
  for (int off = 1; off < 128; off <<= 1) {
    float tv = (q >= off) ? sbuf[q - off] : 0.f;
    __syncthreads();
    sbuf[q] += tv;
    __syncthreads();
  }
  dA_cs[(long long)bi * 128 + q] = sbuf[q];
}

// ---------------------------------------------------------------------------
// S3 (MFMA): Y_diag -> y bf16, local states -> states bf16.
// ---------------------------------------------------------------------------
__global__ __launch_bounds__(256) void ssd_diag_states_k(
    const unsigned short* __restrict__ xBC, const float* __restrict__ dt_s,
    const float* __restrict__ dA_cs, const unsigned short* __restrict__ G,
    unsigned short* __restrict__ y, unsigned short* __restrict__ states) {
  __shared__ unsigned short Mz[128 * 136];  // 34816 B; reused as f32 scratch
  __shared__ unsigned short xdT[64 * 136];
  __shared__ float Acs[128];
  __shared__ float wdec[128];
  const int bx = blockIdx.x;
  const int h = bx & 31, c = (bx >> 5) & 15, b = bx >> 9;
  const int t = threadIdx.x;
  const int w = t >> 6, lane = t & 63, fr = lane & 15, hi = lane >> 4;
  const long long rowbase = (long long)b * 2048 + c * 128;
  const long long abase = ((long long)((b * 32 + h) * 16 + c)) << 7;

  if (t < 128) {
    float a = dA_cs[abase + t];
    Acs[t] = a;
    wdec[t] = __expf(dA_cs[abase + 127] - a);
  }
  {
    int s = t >> 1, p0 = (t & 1) * 32;
    float dtv = dt_s[(rowbase + s) * 32 + h];
    const ushort8v* xv = (const ushort8v*)(xBC + (rowbase + s) * 2304 + h * 64 + p0);
#pragma unroll
    for (int i = 0; i < 4; ++i) {
      ushort8v vv = xv[i];
#pragma unroll
      for (int j = 0; j < 8; ++j) xdT[(p0 + i * 8 + j) * 136 + s] = f32_bf16(bf2f(vv[j]) * dtv);
    }
  }
  __syncthreads();
  {
    int q = t >> 1, s0 = (t & 1) * 64;
    float aq = Acs[q];
    const ushort8v* gv =
        (const ushort8v*)(G + (((long long)(b * 16 + c)) * 128 + q) * 128 + s0);
#pragma unroll
    for (int i = 0; i < 8; ++i) {
      ushort8v gg = gv[i];
      ushort8v mo;
#pragma unroll
      for (int j = 0; j < 8; ++j) {
        int s = s0 + i * 8 + j;
        float m = (s <= q) ? bf2f(gg[j]) * __expf(aq - Acs[s]) : 0.f;
        mo[j] = f32_bf16(m);
      }
      *(ushort8v*)(Mz + q * 136 + s0 + i * 8) = mo;
    }
  }
  __syncthreads();
  const int q0 = w << 5;
  {
    floatx4 acc[2][4];
#pragma unroll
    for (int i = 0; i < 2; ++i)
#pragma unroll
      for (int j = 0; j < 4; ++j) acc[i][j] = (floatx4){0.f, 0.f, 0.f, 0.f};
#pragma unroll
    for (int k0 = 0; k0 < 128; k0 += 32) {
      int kk = k0 + hi * 8;
      bf16x8 a0 = *(const bf16x8*)(Mz + (q0 + fr) * 136 + kk);
      bf16x8 a1 = *(const bf16x8*)(Mz + (q0 + 16 + fr) * 136 + kk);
      bf16x8 bf_[4];
#pragma unroll
      for (int j = 0; j < 4; ++j) bf_[j] = *(const bf16x8*)(xdT + (j * 16 + fr) * 136 + kk);
#pragma unroll
      for (int j = 0; j < 4; ++j) {
        acc[0][j] = __builtin_amdgcn_mfma_f32_16x16x32_bf16(a0, bf_[j], acc[0][j], 0, 0, 0);
        acc[1][j] = __builtin_amdgcn_mfma_f32_16x16x32_bf16(a1, bf_[j], acc[1][j], 0, 0, 0);
      }
    }
    __syncthreads();
    float* scr = (float*)Mz;
#pragma unroll
    for (int i = 0; i < 2; ++i)
#pragma unroll
      for (int r = 0; r < 4; ++r) {
        int q = q0 + i * 16 + hi * 4 + r;
#pragma unroll
        for (int j = 0; j < 4; ++j) scr[q * 68 + j * 16 + fr] = acc[i][j][r];
      }
    __syncthreads();
    {
      int row = t >> 1, colh = (t & 1) * 32;
      unsigned short* yrow = y + (rowbase + row) * 2048 + h * 64 + colh;
      const float* sp = scr + row * 68 + colh;
#pragma unroll
      for (int k = 0; k < 4; ++k) {
        float4 v0 = *(const float4*)(sp + k * 8);
        float4 v1 = *(const float4*)(sp + k * 8 + 4);
        ushort8v o = {f32_bf16(v0.x), f32_bf16(v0.y), f32_bf16(v0.z), f32_bf16(v0.w),
                      f32_bf16(v1.x), f32_bf16(v1.y), f32_bf16(v1.z), f32_bf16(v1.w)};
        *(ushort8v*)(yrow + k * 8) = o;
      }
    }
  }
  __syncthreads();
  {
    int s = t >> 1, n0 = (t & 1) * 64;
    float wd = wdec[s];
    const ushort8v* bv = (const ushort8v*)(xBC + (rowbase + s) * 2304 + 2048 + n0);
#pragma unroll
    for (int i = 0; i < 8; ++i) {
      ushort8v bb = bv[i];
#pragma unroll
      for (int j = 0; j < 8; ++j) Mz[(n0 + i * 8 + j) * 136 + s] = f32_bf16(bf2f(bb[j]) * wd);
    }
  }
  __syncthreads();
  {
    floatx4 acc[2][4];
#pragma unroll
    for (int i = 0; i < 2; ++i)
#pragma unroll
      for (int j = 0; j < 4; ++j) acc[i][j] = (floatx4){0.f, 0.f, 0.f, 0.f};
#pragma unroll
    for (int k0 = 0; k0 < 128; k0 += 32) {
      int kk = k0 + hi * 8;
      bf16x8 a0 = *(const bf16x8*)(Mz + (q0 + fr) * 136 + kk);
      bf16x8 a1 = *(const bf16x8*)(Mz + (q0 + 16 + fr) * 136 + kk);
      bf16x8 bf_[4];
#pragma unroll
      for (int j = 0; j < 4; ++j) bf_[j] = *(const bf16x8*)(xdT + (j * 16 + fr) * 136 + kk);
#pragma unroll
      for (int j = 0; j < 4; ++j) {
        acc[0][j] = __builtin_amdgcn_mfma_f32_16x16x32_bf16(a0, bf_[j], acc[0][j], 0, 0, 0);
        acc[1][j] = __builtin_amdgcn_mfma_f32_16x16x32_bf16(a1, bf_[j], acc[1][j], 0, 0, 0);
      }
    }
    __syncthreads();
    float* scr = (float*)Mz;
#pragma unroll
    for (int i = 0; i < 2; ++i)
#pragma unroll
      for (int j = 0; j < 4; ++j) {
        int p = j * 16 + fr;
        int n = q0 + i * 16 + hi * 4;
#pragma unroll
        for (int r = 0; r < 4; ++r) scr[p * 132 + n + r] = acc[i][j][r];
      }
    __syncthreads();
    {
      unsigned short* st = states + (long long)bx * 8192;
      int p = t >> 2, nh = (t & 3) * 32;
      unsigned short* strow = st + p * 128 + nh;
      const float* sp = scr + p * 132 + nh;
#pragma unroll
      for (int k = 0; k < 4; ++k) {
        float4 v0 = *(const float4*)(sp + k * 8);
        float4 v1 = *(const float4*)(sp + k * 8 + 4);
        ushort8v o = {f32_bf16(v0.x), f32_bf16(v0.y), f32_bf16(v0.z), f32_bf16(v0.w),
                      f32_bf16(v1.x), f32_bf16(v1.y), f32_bf16(v1.z), f32_bf16(v1.w)};
        *(ushort8v*)(strow + k * 8) = o;
      }
    }
  }
}

// ---------------------------------------------------------------------------
// Inter-chunk scan: 256 blocks (b,h,seg), ushort8 RMW, 8 elems/thread.
// ---------------------------------------------------------------------------
__global__ __launch_bounds__(256) void ssd_scan_k(const float* __restrict__ dA_cs,
                                                  unsigned short* __restrict__ states) {
  int seg = blockIdx.x & 3;
  int h = (blockIdx.x >> 2) & 31;
  int b = blockIdx.x >> 7;
  int t = threadIdx.x;
  int e0 = seg * 2048 + t * 8;
  float carry[8];
#pragma unroll
  for (int i = 0; i < 8; ++i) carry[i] = 0.f;
  for (int c = 0; c < 16; ++c) {
    long long base = ((long long)((b * 16 + c) * 32 + h)) * 8192;
    float dec = __expf(dA_cs[(((long long)((b * 32 + h) * 16 + c)) << 7) + 127]);
    ushort8v v = *(const ushort8v*)(states + base + e0);
    ushort8v o;
#pragma unroll
    for (int i = 0; i < 8; ++i) {
      float local = bf2f(v[i]);
      o[i] = f32_bf16(carry[i]);
      carry[i] = dec * carry[i] + local;
    }
    *(ushort8v*)(states + base + e0) = o;
  }
}

// ---------------------------------------------------------------------------
// Y_off + D-skip (MFMA): acc via LDS -> vectorized ushort8 RMW of y.
// ---------------------------------------------------------------------------
__global__ __launch_bounds__(256) void ssd_off_k(const unsigned short* __restrict__ xBC,
                                                 const float* __restrict__ dA_cs,
                                                 const unsigned short* __restrict__ states,
                                                 const float* __restrict__ Dvec,
                                                 unsigned short* __restrict__ y) {
  __shared__ float eA[128];
  __shared__ float scr[128 * 68];
  const int bx = blockIdx.x;
  const int h = bx & 31, c = (bx >> 5) & 15, b = bx >> 9;
  const int t = threadIdx.x;
  const int w = t >> 6, lane = t & 63, fr = lane & 15, hi = lane >> 4;
  const long long rowbase = (long long)b * 2048 + c * 128;
  const long long abase = ((long long)((b * 32 + h) * 16 + c)) << 7;
  if (t < 128) eA[t] = __expf(dA_cs[abase + t]);
  __syncthreads();

  const unsigned short* st = states + (long long)bx * 8192;
  const int q0 = w << 5;
  floatx4 acc[2][4];
#pragma unroll
  for (int i = 0; i < 2; ++i)
#pragma unroll
    for (int j = 0; j < 4; ++j) acc[i][j] = (floatx4){0.f, 0.f, 0.f, 0.f};

#pragma unroll
  for (int k0 = 0; k0 < 128; k0 += 32) {
    int kk = k0 + hi * 8;
    bf16x8 a0 = *(const bf16x8*)(xBC + (rowbase + q0 + fr) * 2304 + 2176 + kk);
    bf16x8 a1 = *(const bf16x8*)(xBC + (rowbase + q0 + 16 + fr) * 2304 + 2176 + kk);
    bf16x8 bf_[4];
#pragma unroll
    for (int j = 0; j < 4; ++j) bf_[j] = *(const bf16x8*)(st + (j * 16 + fr) * 128 + kk);
#pragma unroll
    for (int j = 0; j < 4; ++j) {
      acc[0][j] = __builtin_amdgcn_mfma_f32_16x16x32_bf16(a0, bf_[j], acc[0][j], 0, 0, 0);
      acc[1][j] = __builtin_amdgcn_mfma_f32_16x16x32_bf16(a1, bf_[j], acc[1][j], 0, 0, 0);
    }
  }

#pragma unroll
  for (int i = 0; i < 2; ++i)
#pragma unroll
    for (int r = 0; r < 4; ++r) {
      int q = q0 + i * 16 + hi * 4 + r;
#pragma unroll
      for (int j = 0; j < 4; ++j) scr[q * 68 + j * 16 + fr] = acc[i][j][r];
    }
  __syncthreads();
  {
    float Dh = Dvec[h];
    int row = t >> 1, colh = (t & 1) * 32;
    float e = eA[row];
    const unsigned short* xrow = xBC + (rowbase + row) * 2304 + h * 64 + colh;
    unsigned short* yrow = y + (rowbase + row) * 2048 + h * 64 + colh;
    const float* sp = scr + row * 68 + colh;
#pragma unroll
    for (int k = 0; k < 4; ++k) {
      ushort8v yv = *(const ushort8v*)(yrow + k * 8);
      ushort8v xv = *(const ushort8v*)(xrow + k * 8);
      float4 a0 = *(const float4*)(sp + k * 8);
      float4 a1 = *(const float4*)(sp + k * 8 + 4);
      float av[8] = {a0.x, a0.y, a0.z, a0.w, a1.x, a1.y, a1.z, a1.w};
      ushort8v o;
#pragma unroll
      for (int e2 = 0; e2 < 8; ++e2)
        o[e2] = f32_bf16(bf2f(yv[e2]) + e * av[e2] + Dh * bf2f(xv[e2]));
      *(ushort8v*)(yrow + k * 8) = o;
    }
  }
}

// ---------------------------------------------------------------------------
extern "C" void kernel_launch(void* const* d_in, const int* in_sizes, int n_in, void* d_out,
                              int out_size, void* d_ws, size_t ws_size, hipStream_t stream) {
  const float* hs = (const float*)d_in[0];
  const float* w_ln1 = (const float*)d_in[1];
  const float* w_in = (const float*)d_in[2];
  const float* w_conv = (const float*)d_in[3];
  const float* b_conv = (const float*)d_in[4];
  const float* dt_bias = (const float*)d_in[5];
  const float* A_log = (const float*)d_in[6];
  const float* Dvec = (const float*)d_in[7];
  const float* w_mnorm = (const float*)d_in[8];
  const float* w_out = (const float*)d_in[9];
  const float* w_ln2 = (const float*)d_in[10];
  const float* w_gate = (const float*)d_in[11];
  const float* w_up = (const float*)d_in[12];
  const float* w_down = (const float*)d_in[13];
  float* out = (float*)d_out;
  const int M = 4096;

  char* ws = (char*)d_ws;
  const size_t R0 = 0;
  const size_t R1 = 33554432;
  const size_t R1b = R1 + 33554432;
  const size_t R2 = 71303168;
  const size_t R3 = 90177536;
  const size_t R4 = 107544576;
  const size_t W0 = 108068864;
  const size_t NEED = 133234688;

  if (ws_size < NEED) {
    hipLaunchKernelGGL(zero_out_k, dim3((out_size + 255) / 256), dim3(256), 0, stream, out,
                       (long long)out_size);
    return;
  }

  unsigned short* z = (unsigned short*)(ws + R0);
  unsigned short* act = (unsigned short*)(ws + R0);
  float* oproj_parts = (float*)(ws + R0);
  unsigned short* xraw = (unsigned short*)(ws + R1);
  unsigned short* states = (unsigned short*)(ws + R1);
  unsigned short* ybuf = (unsigned short*)(ws + R1 + 16777216);
  float* down_parts = (float*)(ws + R1);
  unsigned short* wbf_out = (unsigned short*)(ws + R1b);
  unsigned short* xBC = (unsigned short*)(ws + R2);
  unsigned short* ygn = (unsigned short*)(ws + R2);
  unsigned short* h2 = (unsigned short*)(ws + R2);
  unsigned short* hnorm = (unsigned short*)(ws + R3);
  unsigned short* wbf_in = (unsigned short*)(ws + R3 + 8388608);
  float* dt_s = (float*)(ws + R3);
  float* dA_cs = (float*)(ws + R3 + 524288);
  unsigned short* Gbuf = (unsigned short*)(ws + R3 + 1048576);
  float* mh = (float*)(ws + R3);
  float* dtraw = (float*)(ws + R4);
  unsigned short* wbf_gate = (unsigned short*)(ws + W0);
  unsigned short* wbf_up = (unsigned short*)(ws + W0 + 8388608);
  unsigned short* wbf_down = (unsigned short*)(ws + W0 + 16777216);

  // s1: rmsnorm(ln1) -> hnorm bf16
  hipLaunchKernelGGL(rmsnorm1024_bf16_k, dim3(M), dim3(256), 0, stream, hs, w_ln1, hnorm, 1e-6f);
  // s2: ALL weight conversions in one launch
  hipLaunchKernelGGL(wconv_all_k, dim3(18720), dim3(256), 0, stream, w_in, w_gate, w_up, w_down,
                     w_out, wbf_in, wbf_gate, wbf_up, wbf_down, wbf_out);
  // s3: in_proj -> z bf16 / xraw bf16 / dtraw fp32 (BN=128: 2+ blocks/CU)
  hipLaunchKernelGGL((gemm128<1, 128>), dim3(16, 32, 1), dim3(256), 0, stream, hnorm, wbf_in,
                     (void*)z, (const unsigned short*)nullptr, 1024, 1024, 1024, 2048, 0LL, 0LL,
                     0LL);
  hipLaunchKernelGGL((gemm128<1, 128>), dim3(18, 32, 1), dim3(256), 0, stream, hnorm,
                     wbf_in + 2048 * 1024, (void*)xraw, (const unsigned short*)nullptr, 1024, 1024,
                     1024, 2304, 0LL, 0LL, 0LL);
  hipLaunchKernelGGL((gemm_small_nt<1>), dim3(1, 64, 1), dim3(256), 0, stream, hnorm,
                     wbf_in + 4352 * 1024, dtraw, M, 32, 1024, 1024, 1024, 32);
  // s4: conv + silu -> xBC bf16
  hipLaunchKernelGGL(conv_silu_k, dim3(4608), dim3(256), 0, stream, xraw, w_conv, b_conv, xBC);
  // s5+s6 fused: dt softplus + dA cumsum
  hipLaunchKernelGGL(dA_cumsum_k, dim3(1024), dim3(128), 0, stream, dtraw, dt_bias, A_log, dt_s,
                     dA_cs);
  // s7: G = C @ B^T per chunk, stored bf16
  hipLaunchKernelGGL((gemm128<1, 128>), dim3(1, 1, 32), dim3(256), 0, stream, xBC + 2176,
                     xBC + 2048, (void*)Gbuf, (const unsigned short*)nullptr, 128, 2304, 2304, 128,
                     294912LL, 294912LL, 16384LL);
  // s8: Y_diag + local states (MFMA)
  hipLaunchKernelGGL(ssd_diag_states_k, dim3(1024), dim3(256), 0, stream, xBC, dt_s, dA_cs, Gbuf,
                     ybuf, states);
  // s9: inter-chunk scan
  hipLaunchKernelGGL(ssd_scan_k, dim3(256), dim3(256), 0, stream, dA_cs, states);
  // s10: Y_off + D-skip (MFMA)
  hipLaunchKernelGGL(ssd_off_k, dim3(1024), dim3(256), 0, stream, xBC, dA_cs, states, Dvec, ybuf);
  // s11: gated rmsnorm -> ygn bf16
  hipLaunchKernelGGL(gated_rmsnorm2048_k, dim3(M), dim3(256), 0, stream, ybuf, z, w_mnorm, ygn,
                     1e-5f);
  // s12: out_proj, BN=128 split-K=2 -> 512 blocks
  hipLaunchKernelGGL((gemm128<0, 128>), dim3(8, 32, 2), dim3(256), 0, stream, ygn, wbf_out,
                     (void*)oproj_parts, (const unsigned short*)nullptr, 1024, 2048, 2048, 1024,
                     1024LL, 1024LL, 4194304LL);
  // s13: mh = hs + sum(partials); h2 = rmsnorm(mh, ln2)  [fused]
  hipLaunchKernelGGL(add_rmsnorm_k, dim3(M), dim3(256), 0, stream, hs, oproj_parts, 4194304LL, 2,
                     w_ln2, mh, h2, 1e-6f);
  // s15+s16 fused dual GEMM: act = silu(h2@wgate^T) * (h2@wup^T), no upo.
  hipLaunchKernelGGL(gemm128_dual, dim3(32, 32, 1), dim3(256), 0, stream, h2, wbf_gate, wbf_up,
                     act, 1024, 1024, 1024, 4096);
  // s17: down, BN=128 split-K=2 -> 512 blocks
  hipLaunchKernelGGL((gemm128<0, 128>), dim3(8, 32, 2), dim3(256), 0, stream, act, wbf_down,
                     (void*)down_parts, (const unsigned short*)nullptr, 2048, 4096, 4096, 1024,
                     2048LL, 2048LL, 4194304LL);
  // s18: out = mh + sum(partials)
  hipLaunchKernelGGL(addn_f32_k, dim3(4096), dim3(256), 0, stream, mh, down_parts, 4194304LL, 2,
                     out, 1048576LL);
}

// Round 11
// 510.329 us; speedup vs baseline: 1.0255x; 1.0031x over previous
//
#include <hip/hip_runtime.h>

#define DEV static __device__ __forceinline__

typedef short bf16x8 __attribute__((ext_vector_type(8)));
typedef float floatx4 __attribute__((ext_vector_type(4)));
typedef unsigned short ushort4v __attribute__((ext_vector_type(4)));
typedef unsigned short ushort8v __attribute__((ext_vector_type(8)));

DEV unsigned short f32_bf16(float f) {
  unsigned int u = __builtin_bit_cast(unsigned int, f);
  u = u + 0x7fffu + ((u >> 16) & 1u);
  return (unsigned short)(u >> 16);
}
DEV float bf2f(unsigned short u) {
  unsigned int v = ((unsigned int)u) << 16;
  return __builtin_bit_cast(float, v);
}
DEV float sigmoidf_(float x) { return 1.0f / (1.0f + __expf(-x)); }
DEV float siluf_(float x) { return x * sigmoidf_(x); }

#define GLD_LDS16(g, l)                                                              \
  __builtin_amdgcn_global_load_lds((const __attribute__((address_space(1))) void*)(g), \
                                   (__attribute__((address_space(3))) void*)(l), 16, 0, 0)

// ---------------------------------------------------------------------------
// Pipelined MFMA GEMM: C[M,N] = A[M,K] @ B[N,K]^T, bf16 in, 128xBN block tile.
// DOUBLE-buffered LDS, 2-barrier loop, counted vmcnt (R7-verified).
// MODE 0: fp32 store. MODE 1: bf16. MODE 3: dual-destination bf16 (in_proj
// fused z|xraw: n-tiles with n0<2048 -> Cv ldc 2048; else -> other ldc 2304,
// col n0-2048). Epilogue: f32 acc -> LDS [32][BN+4] -> ushort8 stores.
// ---------------------------------------------------------------------------
template <int MODE, int BN>
__global__ __launch_bounds__(256) void gemm128(
    const unsigned short* __restrict__ A, const unsigned short* __restrict__ B,
    void* __restrict__ Cv, const unsigned short* __restrict__ other,
    int K, int lda, int ldb, int ldc, long long bsA, long long bsB, long long bsC) {
  constexpr int NBG = BN / 64;           // B gload_lds per wave per stage (2|4)
  constexpr int NJ = BN / 32;            // j-fragments per wave (4|8)
  constexpr int BUFSZ = 4096 + BN * 32;  // ushorts per buffer (A 128x32 + B BNx32)
  __shared__ unsigned short S[2 * BUFSZ];
  A += (long long)blockIdx.z * bsA;
  B += (long long)blockIdx.z * bsB;
  const long long coff = (long long)blockIdx.z * bsC;
  const int tid = threadIdx.x;
  const int w = tid >> 6, lane = tid & 63;

  // GM=4 supertile swizzle: consecutive blocks walk M within a 4-row group.
  const int nbx = gridDim.x, nby = gridDim.y;
  const int GM = 4;
  int bid = blockIdx.y * nbx + blockIdx.x;
  int gid = bid / (GM * nbx);
  int rem = bid - gid * (GM * nbx);
  int gsz = min(GM, nby - gid * GM);
  int mtile = gid * GM + rem % gsz;
  int ntile = rem / gsz;
  const int m0 = mtile << 7, n0 = ntile * BN;

  const int srow = lane >> 2;
  const int schunk = ((lane & 3) ^ (srow & 3)) * 8;  // pre-swizzled global src
  const unsigned short* ag0 = A + (long long)(m0 + w * 32 + srow) * lda + schunk;
  const unsigned short* ag1 = ag0 + (long long)16 * lda;
  const unsigned short* bgp[NBG];
#pragma unroll
  for (int ii = 0; ii < NBG; ++ii)
    bgp[ii] = B + (long long)(n0 + w * (BN / 4) + srow + 16 * ii) * ldb + schunk;

  auto STAGE = [&](int buf, int k0) {
    unsigned short* as_ = S + buf * BUFSZ;
    unsigned short* bs_ = as_ + 4096;
    GLD_LDS16(ag0 + k0, as_ + w * 1024 + lane * 8);
    GLD_LDS16(ag1 + k0, as_ + w * 1024 + lane * 8 + 512);
#pragma unroll
    for (int ii = 0; ii < NBG; ++ii)
      GLD_LDS16(bgp[ii] + k0, bs_ + w * (NBG * 512) + ii * 512 + lane * 8);
  };

  const int wr = (w >> 1) << 6;
  const int wc = (w & 1) * (BN / 2);
  const int fr = lane & 15;
  const int slot = (((lane >> 4) ^ (fr & 3))) << 3;
  const int r0 = (lane >> 4) << 2;

  floatx4 acc[4][NJ];
#pragma unroll
  for (int i = 0; i < 4; ++i)
#pragma unroll
    for (int j = 0; j < NJ; ++j) acc[i][j] = (floatx4){0.f, 0.f, 0.f, 0.f};

  const int nsteps = K >> 5;
  STAGE(0, 0);
  if (nsteps > 1) STAGE(1, 32);

  for (int t = 0; t < nsteps; ++t) {
    if (t < nsteps - 1) {
      if constexpr (NBG == 2) {
        asm volatile("s_waitcnt vmcnt(4)" ::: "memory");
      } else {
        asm volatile("s_waitcnt vmcnt(6)" ::: "memory");
      }
    } else {
      asm volatile("s_waitcnt vmcnt(0)" ::: "memory");
    }
    __builtin_amdgcn_s_barrier();
    __builtin_amdgcn_sched_barrier(0);
    const unsigned short* Ab = S + (t & 1) * BUFSZ;
    const unsigned short* Bb = Ab + 4096;
    bf16x8 af[4], bf_[NJ];
#pragma unroll
    for (int i = 0; i < 4; ++i)
      af[i] = *(const bf16x8*)(Ab + (wr + i * 16 + fr) * 32 + slot);
#pragma unroll
    for (int j = 0; j < NJ; ++j)
      bf_[j] = *(const bf16x8*)(Bb + (wc + j * 16 + fr) * 32 + slot);
#pragma unroll
    for (int i = 0; i < 4; ++i)
#pragma unroll
      for (int j = 0; j < NJ; ++j)
        acc[i][j] = __builtin_amdgcn_mfma_f32_16x16x32_bf16(af[i], bf_[j], acc[i][j], 0, 0, 0);
    __builtin_amdgcn_sched_barrier(0);
    __builtin_amdgcn_s_barrier();
    if (t + 2 < nsteps) STAGE(t & 1, (t + 2) * 32);
  }

  if constexpr (MODE == 0) {
#pragma unroll
    for (int i = 0; i < 4; ++i) {
#pragma unroll
      for (int j = 0; j < NJ; ++j) {
        long long base = (long long)(m0 + wr + i * 16 + r0) * ldc + (n0 + wc + j * 16 + fr);
#pragma unroll
        for (int r = 0; r < 4; ++r) {
          ((float*)Cv)[coff + base + (long long)r * ldc] = acc[i][j][r];
        }
      }
    }
  } else {
    // Destination select (MODE 3: z-part vs xraw-part of in_proj).
    unsigned short* dst;
    int ldd, ncol;
    if constexpr (MODE == 3) {
      if (n0 < 2048) {
        dst = (unsigned short*)Cv;
        ldd = 2048;
        ncol = n0;
      } else {
        dst = (unsigned short*)const_cast<unsigned short*>(other);
        ldd = 2304;
        ncol = n0 - 2048;
      }
    } else {
      dst = (unsigned short*)Cv;
      ldd = ldc;
      ncol = n0;
    }
    constexpr int PAD = BN + 4;
    float* scr = (float*)S;
    const int row_l = tid >> 3;      // 0..31
    const int col0 = (tid & 7) * 8;  // 0..56 step 8
    __syncthreads();
#pragma unroll
    for (int pass = 0; pass < 4; ++pass) {
      if ((w >> 1) == (pass >> 1)) {
#pragma unroll
        for (int ii = 0; ii < 2; ++ii) {
          int i = (pass & 1) * 2 + ii;
          int rl = i * 16 + r0 - (pass & 1) * 32;  // 0..31
#pragma unroll
          for (int j = 0; j < NJ; ++j) {
            int col = wc + j * 16 + fr;
#pragma unroll
            for (int r = 0; r < 4; ++r) scr[(rl + r) * PAD + col] = acc[i][j][r];
          }
        }
      }
      __syncthreads();
      long long grow = m0 + pass * 32 + row_l;
      long long gbase = coff + grow * (long long)ldd + ncol;
      const float* srow_p = scr + row_l * PAD;
#pragma unroll
      for (int k = 0; k < BN / 64; ++k) {
        int col = col0 + k * 64;
        float v[8];
        *(float4*)&v[0] = *(const float4*)(srow_p + col);
        *(float4*)&v[4] = *(const float4*)(srow_p + col + 4);
        ushort8v o;
#pragma unroll
        for (int e = 0; e < 8; ++e) o[e] = f32_bf16(v[e]);
        *(ushort8v*)(dst + gbase + col) = o;
      }
      __syncthreads();
    }
  }
}

// ---------------------------------------------------------------------------
// Fused gate+up swiglu dual GEMM, 128x128 tile. TRIPLE-buffered LDS (72KB),
// single barrier per K-step, stage(t+2) issued BEFORE compute (R4-verified
// schedule): regs already cap occupancy at 2 blocks/CU (96 VGPR + 128 AGPR),
// so the 72KB LDS costs nothing and the deeper lookahead covers HBM latency
// under the MFMA phase. Counted vmcnt(6) (one 6-load stage stays in flight).
// Race ledger (R4): RAW own-wave vmcnt + top barrier; WAR buf[(t+2)%3] ==
// buf[(t-1)%3], readers finished before this iter's barrier; WAW none.
// ---------------------------------------------------------------------------
__global__ __launch_bounds__(256, 2) void gemm128_dual(
    const unsigned short* __restrict__ A, const unsigned short* __restrict__ Bg,
    const unsigned short* __restrict__ Bu, unsigned short* __restrict__ C,
    int K, int lda, int ldb, int ldc) {
  __shared__ unsigned short S[3 * 12288];
  const int tid = threadIdx.x;
  const int w = tid >> 6, lane = tid & 63;
  const int nbx = gridDim.x, nby = gridDim.y;
  const int GM = 4;
  int bid = blockIdx.y * nbx + blockIdx.x;
  int gid = bid / (GM * nbx);
  int rem = bid - gid * (GM * nbx);
  int gsz = min(GM, nby - gid * GM);
  int mtile = gid * GM + rem % gsz;
  int ntile = rem / gsz;
  const int m0 = mtile << 7, n0 = ntile << 7;

  const int srow = lane >> 2;
  const int schunk = ((lane & 3) ^ (srow & 3)) * 8;
  const unsigned short* ag0 = A + (long long)(m0 + w * 32 + srow) * lda + schunk;
  const unsigned short* ag1 = ag0 + (long long)16 * lda;
  const unsigned short* gg0 = Bg + (long long)(n0 + w * 32 + srow) * ldb + schunk;
  const unsigned short* gg1 = gg0 + (long long)16 * ldb;
  const unsigned short* ug0 = Bu + (long long)(n0 + w * 32 + srow) * ldb + schunk;
  const unsigned short* ug1 = ug0 + (long long)16 * ldb;

  auto STAGE = [&](int buf, int k0) {
    unsigned short* as_ = S + buf * 12288;
    unsigned short* gs_ = as_ + 4096;
    unsigned short* us_ = as_ + 8192;
    GLD_LDS16(ag0 + k0, as_ + w * 1024 + lane * 8);
    GLD_LDS16(ag1 + k0, as_ + w * 1024 + lane * 8 + 512);
    GLD_LDS16(gg0 + k0, gs_ + w * 1024 + lane * 8);
    GLD_LDS16(gg1 + k0, gs_ + w * 1024 + lane * 8 + 512);
    GLD_LDS16(ug0 + k0, us_ + w * 1024 + lane * 8);
    GLD_LDS16(ug1 + k0, us_ + w * 1024 + lane * 8 + 512);
  };

  const int wr = (w >> 1) << 6;
  const int wc = (w & 1) << 6;
  const int fr = lane & 15;
  const int slot = (((lane >> 4) ^ (fr & 3))) << 3;
  const int r0 = (lane >> 4) << 2;

  floatx4 accg[4][4], accu[4][4];
#pragma unroll
  for (int i = 0; i < 4; ++i)
#pragma unroll
    for (int j = 0; j < 4; ++j) {
      accg[i][j] = (floatx4){0.f, 0.f, 0.f, 0.f};
      accu[i][j] = (floatx4){0.f, 0.f, 0.f, 0.f};
    }

  const int nsteps = K >> 5;
  STAGE(0, 0);
  if (nsteps > 1) STAGE(1, 32);

  int cur = 0, nxt2 = 2;
  for (int t = 0; t < nsteps; ++t) {
    if (t < nsteps - 1) {
      asm volatile("s_waitcnt vmcnt(6)" ::: "memory");
    } else {
      asm volatile("s_waitcnt vmcnt(0)" ::: "memory");
    }
    __builtin_amdgcn_s_barrier();
    __builtin_amdgcn_sched_barrier(0);
    if (t + 2 < nsteps) STAGE(nxt2, (t + 2) * 32);
    __builtin_amdgcn_sched_barrier(0);
    const unsigned short* Ab = S + cur * 12288;
    const unsigned short* Gb = Ab + 4096;
    const unsigned short* Ub = Ab + 8192;
    bf16x8 af[4], gf[4], uf[4];
#pragma unroll
    for (int i = 0; i < 4; ++i)
      af[i] = *(const bf16x8*)(Ab + (wr + i * 16 + fr) * 32 + slot);
#pragma unroll
    for (int j = 0; j < 4; ++j) {
      gf[j] = *(const bf16x8*)(Gb + (wc + j * 16 + fr) * 32 + slot);
      uf[j] = *(const bf16x8*)(Ub + (wc + j * 16 + fr) * 32 + slot);
    }
#pragma unroll
    for (int i = 0; i < 4; ++i)
#pragma unroll
      for (int j = 0; j < 4; ++j) {
        accg[i][j] = __builtin_amdgcn_mfma_f32_16x16x32_bf16(af[i], gf[j], accg[i][j], 0, 0, 0);
        accu[i][j] = __builtin_amdgcn_mfma_f32_16x16x32_bf16(af[i], uf[j], accu[i][j], 0, 0, 0);
      }
    __builtin_amdgcn_sched_barrier(0);
    cur = (cur == 2) ? 0 : cur + 1;
    nxt2 = (nxt2 == 2) ? 0 : nxt2 + 1;
  }

  // In-register swiglu, then the verified 4-pass LDS-transpose epilogue.
#pragma unroll
  for (int i = 0; i < 4; ++i)
#pragma unroll
    for (int j = 0; j < 4; ++j)
#pragma unroll
      for (int r = 0; r < 4; ++r) accg[i][j][r] = siluf_(accg[i][j][r]) * accu[i][j][r];

  constexpr int PAD = 132;
  float* scr = (float*)S;
  const int row_l = tid >> 3;
  const int col0 = (tid & 7) * 8;
  __syncthreads();
#pragma unroll
  for (int pass = 0; pass < 4; ++pass) {
    if ((w >> 1) == (pass >> 1)) {
#pragma unroll
      for (int ii = 0; ii < 2; ++ii) {
        int i = (pass & 1) * 2 + ii;
        int rl = i * 16 + r0 - (pass & 1) * 32;
#pragma unroll
        for (int j = 0; j < 4; ++j) {
          int col = wc + j * 16 + fr;
#pragma unroll
          for (int r = 0; r < 4; ++r) scr[(rl + r) * PAD + col] = accg[i][j][r];
        }
      }
    }
    __syncthreads();
    long long grow = m0 + pass * 32 + row_l;
    long long gbase = grow * (long long)ldc + n0;
    const float* srow_p = scr + row_l * PAD;
#pragma unroll
    for (int k = 0; k < 2; ++k) {
      int col = col0 + k * 64;
      float v[8];
      *(float4*)&v[0] = *(const float4*)(srow_p + col);
      *(float4*)&v[4] = *(const float4*)(srow_p + col + 4);
      ushort8v o;
#pragma unroll
      for (int e = 0; e < 8; ++e) o[e] = f32_bf16(v[e]);
      *(ushort8v*)(C + gbase + col) = o;
    }
    __syncthreads();
  }
}

// ---------------------------------------------------------------------------
// small GEMM (direct-from-global), used only for the N=32 dt projection.
// ---------------------------------------------------------------------------
template <int WM>
__global__ __launch_bounds__(256) void gemm_small_nt(
    const unsigned short* __restrict__ A, const unsigned short* __restrict__ B,
    float* __restrict__ C, int M, int N, int K, int lda, int ldb, int ldc) {
  const int w = threadIdx.x >> 6;
  const int lane = threadIdx.x & 63;
  const int lm = lane & 15;
  const int ko = (lane >> 4) << 3;
  const int bn0 = blockIdx.x << 6;
  const int m_base = blockIdx.y * (WM * 64) + w * (WM * 16);

  const unsigned short* arow[WM];
#pragma unroll
  for (int i = 0; i < WM; ++i) arow[i] = A + (long long)(m_base + i * 16 + lm) * lda + ko;
  int nv = (N - bn0) >> 4;
  nv = nv > 4 ? 4 : nv;
  const unsigned short* brow[4];
#pragma unroll
  for (int j = 0; j < 4; ++j) {
    int nr = bn0 + j * 16 + lm;
    brow[j] = B + (long long)(j < nv ? nr : 0) * ldb + ko;
  }
  floatx4 acc[WM][4];
#pragma unroll
  for (int i = 0; i < WM; ++i)
#pragma unroll
    for (int j = 0; j < 4; ++j) acc[i][j] = (floatx4){0.f, 0.f, 0.f, 0.f};
  for (int k0 = 0; k0 < K; k0 += 32) {
    bf16x8 a[WM];
#pragma unroll
    for (int i = 0; i < WM; ++i) a[i] = *(const bf16x8*)(arow[i] + k0);
#pragma unroll
    for (int j = 0; j < 4; ++j) {
      if (j < nv) {
        bf16x8 b = *(const bf16x8*)(brow[j] + k0);
#pragma unroll
        for (int i = 0; i < WM; ++i)
          acc[i][j] = __builtin_amdgcn_mfma_f32_16x16x32_bf16(a[i], b, acc[i][j], 0, 0, 0);
      }
    }
  }
  const int r0 = (lane >> 4) << 2;
#pragma unroll
  for (int i = 0; i < WM; ++i)
#pragma unroll
    for (int j = 0; j < 4; ++j)
      if (j < nv) {
        int col = bn0 + j * 16 + lm;
        long long base = (long long)(m_base + i * 16 + r0) * ldc + col;
#pragma unroll
        for (int r = 0; r < 4; ++r) C[base + (long long)r * ldc] = acc[i][j][r];
      }
}

// ---------------------------------------------------------------------------
// All weight conversions fused into one kernel (5 ranges, float4 units).
// ---------------------------------------------------------------------------
__global__ __launch_bounds__(256) void wconv_all_k(
    const float* __restrict__ w_in, const float* __restrict__ w_gate,
    const float* __restrict__ w_up, const float* __restrict__ w_down,
    const float* __restrict__ w_out, unsigned short* __restrict__ d_in_,
    unsigned short* __restrict__ d_gate, unsigned short* __restrict__ d_up,
    unsigned short* __restrict__ d_down, unsigned short* __restrict__ d_out_) {
  long long j = (long long)blockIdx.x * 256 + threadIdx.x;
  const float* src;
  unsigned short* dst;
  if (j < 1122304) {
    src = w_in; dst = d_in_;
  } else if ((j -= 1122304) < 1048576) {
    src = w_gate; dst = d_gate;
  } else if ((j -= 1048576) < 1048576) {
    src = w_up; dst = d_up;
  } else if ((j -= 1048576) < 1048576) {
    src = w_down; dst = d_down;
  } else if ((j -= 1048576) < 524288) {
    src = w_out; dst = d_out_;
  } else {
    return;
  }
  float4 v = ((const float4*)src)[j];
  ushort4v o = {f32_bf16(v.x), f32_bf16(v.y), f32_bf16(v.z), f32_bf16(v.w)};
  ((ushort4v*)dst)[j] = o;
}

__global__ __launch_bounds__(256) void zero_out_k(float* __restrict__ o, long long n) {
  long long i = (long long)blockIdx.x * 256 + threadIdx.x;
  if (i < n) o[i] = 0.f;
}

// ---------------------------------------------------------------------------
__global__ __launch_bounds__(256) void rmsnorm1024_bf16_k(const float* __restrict__ x,
                                                          const float* __restrict__ w,
                                                          unsigned short* __restrict__ out,
                                                          float eps) {
  long long row = blockIdx.x;
  int t = threadIdx.x;
  float4 v = ((const float4*)(x + row * 1024))[t];
  float ss = v.x * v.x + v.y * v.y + v.z * v.z + v.w * v.w;
  __shared__ float red[4];
#pragma unroll
  for (int o = 32; o > 0; o >>= 1) ss += __shfl_down(ss, o, 64);
  if ((t & 63) == 0) red[t >> 6] = ss;
  __syncthreads();
  float tot = red[0] + red[1] + red[2] + red[3];
  float sc = rsqrtf(tot * (1.0f / 1024.0f) + eps);
  float4 wv = ((const float4*)w)[t];
  ushort4v o = {f32_bf16(v.x * sc * wv.x), f32_bf16(v.y * sc * wv.y),
                f32_bf16(v.z * sc * wv.z), f32_bf16(v.w * sc * wv.w)};
  ((ushort4v*)(out + row * 1024))[t] = o;
}

// ---------------------------------------------------------------------------
// Fused: mh = hs + sum_{p<np} parts[p]; h2 = bf16(rmsnorm(mh) * w). 1024 cols.
// ---------------------------------------------------------------------------
__global__ __launch_bounds__(256) void add_rmsnorm_k(const float* __restrict__ hs,
                                                     const float* __restrict__ parts,
                                                     long long pstride, int np,
                                                     const float* __restrict__ w,
                                                     float* __restrict__ mh,
                                                     unsigned short* __restrict__ h2, float eps) {
  long long row = blockIdx.x;
  int t = threadIdx.x;
  float4 v = ((const float4*)(hs + row * 1024))[t];
  for (int p = 0; p < np; ++p) {
    float4 u = ((const float4*)(parts + p * pstride + row * 1024))[t];
    v.x += u.x;
    v.y += u.y;
    v.z += u.z;
    v.w += u.w;
  }
  ((float4*)(mh + row * 1024))[t] = v;
  float ss = v.x * v.x + v.y * v.y + v.z * v.z + v.w * v.w;
  __shared__ float red[4];
#pragma unroll
  for (int o = 32; o > 0; o >>= 1) ss += __shfl_down(ss, o, 64);
  if ((t & 63) == 0) red[t >> 6] = ss;
  __syncthreads();
  float tot = red[0] + red[1] + red[2] + red[3];
  float sc = rsqrtf(tot * (1.0f / 1024.0f) + eps);
  float4 wv = ((const float4*)w)[t];
  ushort4v o = {f32_bf16(v.x * sc * wv.x), f32_bf16(v.y * sc * wv.y),
                f32_bf16(v.z * sc * wv.z), f32_bf16(v.w * sc * wv.w)};
  ((ushort4v*)(h2 + row * 1024))[t] = o;
}

// ---------------------------------------------------------------------------
__global__ __launch_bounds__(256) void addn_f32_k(const float* __restrict__ a,
                                                  const float* __restrict__ parts,
                                                  long long pstride, int np,
                                                  float* __restrict__ o, long long n4) {
  long long i = (long long)blockIdx.x * 256 + threadIdx.x;
  if (i < n4) {
    float4 x = ((const float4*)a)[i];
    for (int p = 0; p < np; ++p) {
      float4 u = ((const float4*)(parts + p * pstride))[i];
      x.x += u.x;
      x.y += u.y;
      x.z += u.z;
      x.w += u.w;
    }
    ((float4*)o)[i] = x;
  }
}

// ---------------------------------------------------------------------------
__global__ __launch_bounds__(256) void gated_rmsnorm2048_k(const unsigned short* __restrict__ y,
                                                           const unsigned short* __restrict__ z,
                                                           const float* __restrict__ w,
                                                           unsigned short* __restrict__ out,
                                                           float eps) {
  long long row = blockIdx.x;
  int t = threadIdx.x;
  ushort8v yv = ((const ushort8v*)(y + row * 2048))[t];
  ushort8v zv = ((const ushort8v*)(z + row * 2048))[t];
  float g[8];
  float ss = 0.f;
#pragma unroll
  for (int j = 0; j < 8; ++j) {
    g[j] = bf2f(yv[j]) * siluf_(bf2f(zv[j]));
    ss += g[j] * g[j];
  }
  __shared__ float red[4];
#pragma unroll
  for (int o = 32; o > 0; o >>= 1) ss += __shfl_down(ss, o, 64);
  if ((t & 63) == 0) red[t >> 6] = ss;
  __syncthreads();
  float tot = red[0] + red[1] + red[2] + red[3];
  float sc = rsqrtf(tot * (1.0f / 2048.0f) + eps);
  float ww[8];
  *(float4*)&ww[0] = ((const float4*)w)[2 * t];
  *(float4*)&ww[4] = ((const float4*)w)[2 * t + 1];
  ushort8v o;
#pragma unroll
  for (int j = 0; j < 8; ++j) o[j] = f32_bf16(g[j] * sc * ww[j]);
  ((ushort8v*)(out + row * 2048))[t] = o;
}

// ---------------------------------------------------------------------------
// conv + silu: flat (m, cb) grid, 1 vec8 work item per thread.
// ---------------------------------------------------------------------------
__global__ __launch_bounds__(256) void conv_silu_k(const unsigned short* __restrict__ xraw,
                                                   const float* __restrict__ wconv,
                                                   const float* __restrict__ bconv,
                                                   unsigned short* __restrict__ xBC) {
  long long f = (long long)blockIdx.x * 256 + threadIdx.x;
  if (f >= 4096LL * 288) return;
  int m = (int)(f / 288);
  int cb = (int)(f - (long long)m * 288);
  int l = m & 2047;
  int ch0 = cb << 3;
  float acc[8];
  float4 bc0 = ((const float4*)bconv)[cb * 2];
  float4 bc1 = ((const float4*)bconv)[cb * 2 + 1];
  acc[0] = bc0.x; acc[1] = bc0.y; acc[2] = bc0.z; acc[3] = bc0.w;
  acc[4] = bc1.x; acc[5] = bc1.y; acc[6] = bc1.z; acc[7] = bc1.w;
  float4 wv[8];
#pragma unroll
  for (int j = 0; j < 8; ++j) wv[j] = ((const float4*)wconv)[ch0 + j];
#pragma unroll
  for (int k = 0; k < 4; ++k) {
    int lk = l + k - 3;
    if (lk >= 0) {
      ushort8v xv = *(const ushort8v*)(xraw + (long long)(m + k - 3) * 2304 + ch0);
      acc[0] += bf2f(xv[0]) * ((const float*)&wv[0])[k];
      acc[1] += bf2f(xv[1]) * ((const float*)&wv[1])[k];
      acc[2] += bf2f(xv[2]) * ((const float*)&wv[2])[k];
      acc[3] += bf2f(xv[3]) * ((const float*)&wv[3])[k];
      acc[4] += bf2f(xv[4]) * ((const float*)&wv[4])[k];
      acc[5] += bf2f(xv[5]) * ((const float*)&wv[5])[k];
      acc[6] += bf2f(xv[6]) * ((const float*)&wv[6])[k];
      acc[7] += bf2f(xv[7]) * ((const float*)&wv[7])[k];
    }
  }
  ushort8v o;
#pragma unroll
  for (int j = 0; j < 8; ++j) o[j] = f32_bf16(siluf_(acc[j]));
  *(ushort8v*)(xBC + (long long)m * 2304 + ch0) = o;
}

// ---------------------------------------------------------------------------
// Fused dt softplus + dA cumsum.
// ---------------------------------------------------------------------------
__global__ __launch_bounds__(128) void dA_cumsum_k(const float* __restrict__ dtraw,
                                                   const float* __restrict__ dt_bias,
                                                   const float* __restrict__ A_log,
                                                   float* __restrict__ dt_s,
                                                   float* __restrict__ dA_cs) {
  int bi = blockIdx.x;
  int c = bi & 15, h = (bi >> 4) & 31, b = bi >> 9;
  int q = threadIdx.x;
  long long idx = ((long long)(b * 2048 + c * 128 + q)) * 32 + h;
  float xv = dtraw[idx] + dt_bias[h];
  float sp = xv > 20.f ? xv : log1pf(expf(xv));
  dt_s[idx] = sp;
  float A = -expf(A_log[h]);
  float v = sp * A;
  __shared__ float sbuf[128];
  sbuf[q] = v;
  __syncthreads();
  for (int off = 1; off < 128; off <<= 1) {
    float tv = (q >= off) ? sbuf[q - off] : 0.f;
    __syncthreads();
    sbuf[q] += tv;
    __syncthreads();
  }
  dA_cs[(long long)bi * 128 + q] = sbuf[q];
}

// ---------------------------------------------------------------------------
// S3 (MFMA): Y_diag -> y bf16, local states -> states bf16.
// ---------------------------------------------------------------------------
__global__ __launch_bounds__(256) void ssd_diag_states_k(
    const unsigned short* __restrict__ xBC, const float* __restrict__ dt_s,
    const float* __restrict__ dA_cs, const unsigned short* __restrict__ G,
    unsigned short* __restrict__ y, unsigned short* __restrict__ states) {
  __shared__ unsigned short Mz[128 * 136];  // 34816 B; reused as f32 scratch
  __shared__ unsigned short xdT[64 * 136];
  __shared__ float Acs[128];
  __shared__ float wdec[128];
  const int bx = blockIdx.x;
  const int h = bx & 31, c = (bx >> 5) & 15, b = bx >> 9;
  const int t = threadIdx.x;
  const int w = t >> 6, lane = t & 63, fr = lane & 15, hi = lane >> 4;
  const long long rowbase = (long long)b * 2048 + c * 128;
  const long long abase = ((long long)((b * 32 + h) * 16 + c)) << 7;

  if (t < 128) {
    float a = dA_cs[abase + t];
    Acs[t] = a;
    wdec[t] = __expf(dA_cs[abase + 127] - a);
  }
  {
    int s = t >> 1, p0 = (t & 1) * 32;
    float dtv = dt_s[(rowbase + s) * 32 + h];
    const ushort8v* xv = (const ushort8v*)(xBC + (rowbase + s) * 2304 + h * 64 + p0);
#pragma unroll
    for (int i = 0; i < 4; ++i) {
      ushort8v vv = xv[i];
#pragma unroll
      for (int j = 0; j < 8; ++j) xdT[(p0 + i * 8 + j) * 136 + s] = f32_bf16(bf2f(vv[j]) * dtv);
    }
  }
  __syncthreads();
  {
    int q = t >> 1, s0 = (t & 1) * 64;
    float aq = Acs[q];
    const ushort8v* gv =
        (const ushort8v*)(G + (((long long)(b * 16 + c)) * 128 + q) * 128 + s0);
#pragma unroll
    for (int i = 0; i < 8; ++i) {
      ushort8v gg = gv[i];
      ushort8v mo;
#pragma unroll
      for (int j = 0; j < 8; ++j) {
        int s = s0 + i * 8 + j;
        float m = (s <= q) ? bf2f(gg[j]) * __expf(aq - Acs[s]) : 0.f;
        mo[j] = f32_bf16(m);
      }
      *(ushort8v*)(Mz + q * 136 + s0 + i * 8) = mo;
    }
  }
  __syncthreads();
  const int q0 = w << 5;
  {
    floatx4 acc[2][4];
#pragma unroll
    for (int i = 0; i < 2; ++i)
#pragma unroll
      for (int j = 0; j < 4; ++j) acc[i][j] = (floatx4){0.f, 0.f, 0.f, 0.f};
#pragma unroll
    for (int k0 = 0; k0 < 128; k0 += 32) {
      int kk = k0 + hi * 8;
      bf16x8 a0 = *(const bf16x8*)(Mz + (q0 + fr) * 136 + kk);
      bf16x8 a1 = *(const bf16x8*)(Mz + (q0 + 16 + fr) * 136 + kk);
      bf16x8 bf_[4];
#pragma unroll
      for (int j = 0; j < 4; ++j) bf_[j] = *(const bf16x8*)(xdT + (j * 16 + fr) * 136 + kk);
#pragma unroll
      for (int j = 0; j < 4; ++j) {
        acc[0][j] = __builtin_amdgcn_mfma_f32_16x16x32_bf16(a0, bf_[j], acc[0][j], 0, 0, 0);
        acc[1][j] = __builtin_amdgcn_mfma_f32_16x16x32_bf16(a1, bf_[j], acc[1][j], 0, 0, 0);
      }
    }
    __syncthreads();
    float* scr = (float*)Mz;
#pragma unroll
    for (int i = 0; i < 2; ++i)
#pragma unroll
      for (int r = 0; r < 4; ++r) {
        int q = q0 + i * 16 + hi * 4 + r;
#pragma unroll
        for (int j = 0; j < 4; ++j) scr[q * 68 + j * 16 + fr] = acc[i][j][r];
      }
    __syncthreads();
    {
      int row = t >> 1, colh = (t & 1) * 32;
      unsigned short* yrow = y + (rowbase + row) * 2048 + h * 64 + colh;
      const float* sp = scr + row * 68 + colh;
#pragma unroll
      for (int k = 0; k < 4; ++k) {
        float4 v0 = *(const float4*)(sp + k * 8);
        float4 v1 = *(const float4*)(sp + k * 8 + 4);
        ushort8v o = {f32_bf16(v0.x), f32_bf16(v0.y), f32_bf16(v0.z), f32_bf16(v0.w),
                      f32_bf16(v1.x), f32_bf16(v1.y), f32_bf16(v1.z), f32_bf16(v1.w)};
        *(ushort8v*)(yrow + k * 8) = o;
      }
    }
  }
  __syncthreads();
  {
    int s = t >> 1, n0 = (t & 1) * 64;
    float wd = wdec[s];
    const ushort8v* bv = (const ushort8v*)(xBC + (rowbase + s) * 2304 + 2048 + n0);
#pragma unroll
    for (int i = 0; i < 8; ++i) {
      ushort8v bb = bv[i];
#pragma unroll
      for (int j = 0; j < 8; ++j) Mz[(n0 + i * 8 + j) * 136 + s] = f32_bf16(bf2f(bb[j]) * wd);
    }
  }
  __syncthreads();
  {
    floatx4 acc[2][4];
#pragma unroll
    for (int i = 0; i < 2; ++i)
#pragma unroll
      for (int j = 0; j < 4; ++j) acc[i][j] = (floatx4){0.f, 0.f, 0.f, 0.f};
#pragma unroll
    for (int k0 = 0; k0 < 128; k0 += 32) {
      int kk = k0 + hi * 8;
      bf16x8 a0 = *(const bf16x8*)(Mz + (q0 + fr) * 136 + kk);
      bf16x8 a1 = *(const bf16x8*)(Mz + (q0 + 16 + fr) * 136 + kk);
      bf16x8 bf_[4];
#pragma unroll
      for (int j = 0; j < 4; ++j) bf_[j] = *(const bf16x8*)(xdT + (j * 16 + fr) * 136 + kk);
#pragma unroll
      for (int j = 0; j < 4; ++j) {
        acc[0][j] = __builtin_amdgcn_mfma_f32_16x16x32_bf16(a0, bf_[j], acc[0][j], 0, 0, 0);
        acc[1][j] = __builtin_amdgcn_mfma_f32_16x16x32_bf16(a1, bf_[j], acc[1][j], 0, 0, 0);
      }
    }
    __syncthreads();
    float* scr = (float*)Mz;
#pragma unroll
    for (int i = 0; i < 2; ++i)
#pragma unroll
      for (int j = 0; j < 4; ++j) {
        int p = j * 16 + fr;
        int n = q0 + i * 16 + hi * 4;
#pragma unroll
        for (int r = 0; r < 4; ++r) scr[p * 132 + n + r] = acc[i][j][r];
      }
    __syncthreads();
    {
      unsigned short* st = states + (long long)bx * 8192;
      int p = t >> 2, nh = (t & 3) * 32;
      unsigned short* strow = st + p * 128 + nh;
      const float* sp = scr + p * 132 + nh;
#pragma unroll
      for (int k = 0; k < 4; ++k) {
        float4 v0 = *(const float4*)(sp + k * 8);
        float4 v1 = *(const float4*)(sp + k * 8 + 4);
        ushort8v o = {f32_bf16(v0.x), f32_bf16(v0.y), f32_bf16(v0.z), f32_bf16(v0.w),
                      f32_bf16(v1.x), f32_bf16(v1.y), f32_bf16(v1.z), f32_bf16(v1.w)};
        *(ushort8v*)(strow + k * 8) = o;
      }
    }
  }
}

// ---------------------------------------------------------------------------
// Inter-chunk scan: 256 blocks (b,h,seg), ushort8 RMW, 8 elems/thread.
// ---------------------------------------------------------------------------
__global__ __launch_bounds__(256) void ssd_scan_k(const float* __restrict__ dA_cs,
                                                  unsigned short* __restrict__ states) {
  int seg = blockIdx.x & 3;
  int h = (blockIdx.x >> 2) & 31;
  int b = blockIdx.x >> 7;
  int t = threadIdx.x;
  int e0 = seg * 2048 + t * 8;
  float carry[8];
#pragma unroll
  for (int i = 0; i < 8; ++i) carry[i] = 0.f;
  for (int c = 0; c < 16; ++c) {
    long long base = ((long long)((b * 16 + c) * 32 + h)) * 8192;
    float dec = __expf(dA_cs[(((long long)((b * 32 + h) * 16 + c)) << 7) + 127]);
    ushort8v v = *(const ushort8v*)(states + base + e0);
    ushort8v o;
#pragma unroll
    for (int i = 0; i < 8; ++i) {
      float local = bf2f(v[i]);
      o[i] = f32_bf16(carry[i]);
      carry[i] = dec * carry[i] + local;
    }
    *(ushort8v*)(states + base + e0) = o;
  }
}

// ---------------------------------------------------------------------------
// Y_off + D-skip (MFMA): acc via LDS -> vectorized ushort8 RMW of y.
// ---------------------------------------------------------------------------
__global__ __launch_bounds__(256) void ssd_off_k(const unsigned short* __restrict__ xBC,
                                                 const float* __restrict__ dA_cs,
                                                 const unsigned short* __restrict__ states,
                                                 const float* __restrict__ Dvec,
                                                 unsigned short* __restrict__ y) {
  __shared__ float eA[128];
  __shared__ float scr[128 * 68];
  const int bx = blockIdx.x;
  const int h = bx & 31, c = (bx >> 5) & 15, b = bx >> 9;
  const int t = threadIdx.x;
  const int w = t >> 6, lane = t & 63, fr = lane & 15, hi = lane >> 4;
  const long long rowbase = (long long)b * 2048 + c * 128;
  const long long abase = ((long long)((b * 32 + h) * 16 + c)) << 7;
  if (t < 128) eA[t] = __expf(dA_cs[abase + t]);
  __syncthreads();

  const unsigned short* st = states + (long long)bx * 8192;
  const int q0 = w << 5;
  floatx4 acc[2][4];
#pragma unroll
  for (int i = 0; i < 2; ++i)
#pragma unroll
    for (int j = 0; j < 4; ++j) acc[i][j] = (floatx4){0.f, 0.f, 0.f, 0.f};

#pragma unroll
  for (int k0 = 0; k0 < 128; k0 += 32) {
    int kk = k0 + hi * 8;
    bf16x8 a0 = *(const bf16x8*)(xBC + (rowbase + q0 + fr) * 2304 + 2176 + kk);
    bf16x8 a1 = *(const bf16x8*)(xBC + (rowbase + q0 + 16 + fr) * 2304 + 2176 + kk);
    bf16x8 bf_[4];
#pragma unroll
    for (int j = 0; j < 4; ++j) bf_[j] = *(const bf16x8*)(st + (j * 16 + fr) * 128 + kk);
#pragma unroll
    for (int j = 0; j < 4; ++j) {
      acc[0][j] = __builtin_amdgcn_mfma_f32_16x16x32_bf16(a0, bf_[j], acc[0][j], 0, 0, 0);
      acc[1][j] = __builtin_amdgcn_mfma_f32_16x16x32_bf16(a1, bf_[j], acc[1][j], 0, 0, 0);
    }
  }

#pragma unroll
  for (int i = 0; i < 2; ++i)
#pragma unroll
    for (int r = 0; r < 4; ++r) {
      int q = q0 + i * 16 + hi * 4 + r;
#pragma unroll
      for (int j = 0; j < 4; ++j) scr[q * 68 + j * 16 + fr] = acc[i][j][r];
    }
  __syncthreads();
  {
    float Dh = Dvec[h];
    int row = t >> 1, colh = (t & 1) * 32;
    float e = eA[row];
    const unsigned short* xrow = xBC + (rowbase + row) * 2304 + h * 64 + colh;
    unsigned short* yrow = y + (rowbase + row) * 2048 + h * 64 + colh;
    const float* sp = scr + row * 68 + colh;
#pragma unroll
    for (int k = 0; k < 4; ++k) {
      ushort8v yv = *(const ushort8v*)(yrow + k * 8);
      ushort8v xv = *(const ushort8v*)(xrow + k * 8);
      float4 a0 = *(const float4*)(sp + k * 8);
      float4 a1 = *(const float4*)(sp + k * 8 + 4);
      float av[8] = {a0.x, a0.y, a0.z, a0.w, a1.x, a1.y, a1.z, a1.w};
      ushort8v o;
#pragma unroll
      for (int e2 = 0; e2 < 8; ++e2)
        o[e2] = f32_bf16(bf2f(yv[e2]) + e * av[e2] + Dh * bf2f(xv[e2]));
      *(ushort8v*)(yrow + k * 8) = o;
    }
  }
}

// ---------------------------------------------------------------------------
extern "C" void kernel_launch(void* const* d_in, const int* in_sizes, int n_in, void* d_out,
                              int out_size, void* d_ws, size_t ws_size, hipStream_t stream) {
  const float* hs = (const float*)d_in[0];
  const float* w_ln1 = (const float*)d_in[1];
  const float* w_in = (const float*)d_in[2];
  const float* w_conv = (const float*)d_in[3];
  const float* b_conv = (const float*)d_in[4];
  const float* dt_bias = (const float*)d_in[5];
  const float* A_log = (const float*)d_in[6];
  const float* Dvec = (const float*)d_in[7];
  const float* w_mnorm = (const float*)d_in[8];
  const float* w_out = (const float*)d_in[9];
  const float* w_ln2 = (const float*)d_in[10];
  const float* w_gate = (const float*)d_in[11];
  const float* w_up = (const float*)d_in[12];
  const float* w_down = (const float*)d_in[13];
  float* out = (float*)d_out;
  const int M = 4096;

  char* ws = (char*)d_ws;
  const size_t R0 = 0;
  const size_t R1 = 33554432;
  const size_t R1b = R1 + 33554432;
  const size_t R2 = 71303168;
  const size_t R3 = 90177536;
  const size_t R4 = 107544576;
  const size_t W0 = 108068864;
  const size_t NEED = 133234688;

  if (ws_size < NEED) {
    hipLaunchKernelGGL(zero_out_k, dim3((out_size + 255) / 256), dim3(256), 0, stream, out,
                       (long long)out_size);
    return;
  }

  unsigned short* z = (unsigned short*)(ws + R0);
  unsigned short* act = (unsigned short*)(ws + R0);
  float* oproj_parts = (float*)(ws + R0);
  unsigned short* xraw = (unsigned short*)(ws + R1);
  unsigned short* states = (unsigned short*)(ws + R1);
  unsigned short* ybuf = (unsigned short*)(ws + R1 + 16777216);
  float* down_parts = (float*)(ws + R1);
  unsigned short* wbf_out = (unsigned short*)(ws + R1b);
  unsigned short* xBC = (unsigned short*)(ws + R2);
  unsigned short* ygn = (unsigned short*)(ws + R2);
  unsigned short* h2 = (unsigned short*)(ws + R2);
  unsigned short* hnorm = (unsigned short*)(ws + R3);
  unsigned short* wbf_in = (unsigned short*)(ws + R3 + 8388608);
  float* dt_s = (float*)(ws + R3);
  float* dA_cs = (float*)(ws + R3 + 524288);
  unsigned short* Gbuf = (unsigned short*)(ws + R3 + 1048576);
  float* mh = (float*)(ws + R3);
  float* dtraw = (float*)(ws + R4);
  unsigned short* wbf_gate = (unsigned short*)(ws + W0);
  unsigned short* wbf_up = (unsigned short*)(ws + W0 + 8388608);
  unsigned short* wbf_down = (unsigned short*)(ws + W0 + 16777216);

  // s1: rmsnorm(ln1) -> hnorm bf16
  hipLaunchKernelGGL(rmsnorm1024_bf16_k, dim3(M), dim3(256), 0, stream, hs, w_ln1, hnorm, 1e-6f);
  // s2: ALL weight conversions in one launch
  hipLaunchKernelGGL(wconv_all_k, dim3(18720), dim3(256), 0, stream, w_in, w_gate, w_up, w_down,
                     w_out, wbf_in, wbf_gate, wbf_up, wbf_down, wbf_out);
  // s3 fused: in_proj z|xraw in ONE dispatch (N=4352, 34x32=1088 blocks;
  // A-panel shared in L2, no inter-dispatch tail). dt projection separate.
  hipLaunchKernelGGL((gemm128<3, 128>), dim3(34, 32, 1), dim3(256), 0, stream, hnorm, wbf_in,
                     (void*)z, (const unsigned short*)xraw, 1024, 1024, 1024, 2048, 0LL, 0LL, 0LL);
  hipLaunchKernelGGL((gemm_small_nt<1>), dim3(1, 64, 1), dim3(256), 0, stream, hnorm,
                     wbf_in + 4352 * 1024, dtraw, M, 32, 1024, 1024, 1024, 32);
  // s4: conv + silu -> xBC bf16
  hipLaunchKernelGGL(conv_silu_k, dim3(4608), dim3(256), 0, stream, xraw, w_conv, b_conv, xBC);
  // s5+s6 fused: dt softplus + dA cumsum
  hipLaunchKernelGGL(dA_cumsum_k, dim3(1024), dim3(128), 0, stream, dtraw, dt_bias, A_log, dt_s,
                     dA_cs);
  // s7: G = C @ B^T per chunk, stored bf16
  hipLaunchKernelGGL((gemm128<1, 128>), dim3(1, 1, 32), dim3(256), 0, stream, xBC + 2176,
                     xBC + 2048, (void*)Gbuf, (const unsigned short*)nullptr, 128, 2304, 2304, 128,
                     294912LL, 294912LL, 16384LL);
  // s8: Y_diag + local states (MFMA)
  hipLaunchKernelGGL(ssd_diag_states_k, dim3(1024), dim3(256), 0, stream, xBC, dt_s, dA_cs, Gbuf,
                     ybuf, states);
  // s9: inter-chunk scan
  hipLaunchKernelGGL(ssd_scan_k, dim3(256), dim3(256), 0, stream, dA_cs, states);
  // s10: Y_off + D-skip (MFMA)
  hipLaunchKernelGGL(ssd_off_k, dim3(1024), dim3(256), 0, stream, xBC, dA_cs, states, Dvec, ybuf);
  // s11: gated rmsnorm -> ygn bf16
  hipLaunchKernelGGL(gated_rmsnorm2048_k, dim3(M), dim3(256), 0, stream, ybuf, z, w_mnorm, ygn,
                     1e-5f);
  // s12: out_proj, BN=128 split-K=2 -> 512 blocks
  hipLaunchKernelGGL((gemm128<0, 128>), dim3(8, 32, 2), dim3(256), 0, stream, ygn, wbf_out,
                     (void*)oproj_parts, (const unsigned short*)nullptr, 1024, 2048, 2048, 1024,
                     1024LL, 1024LL, 4194304LL);
  // s13: mh = hs + sum(partials); h2 = rmsnorm(mh, ln2)  [fused]
  hipLaunchKernelGGL(add_rmsnorm_k, dim3(M), dim3(256), 0, stream, hs, oproj_parts, 4194304LL, 2,
                     w_ln2, mh, h2, 1e-6f);
  // s15+s16 fused dual GEMM (triple-buffer, 1-barrier pipeline)
  hipLaunchKernelGGL(gemm128_dual, dim3(32, 32, 1), dim3(256), 0, stream, h2, wbf_gate, wbf_up,
                     act, 1024, 1024, 1024, 4096);
  // s17: down, BN=128 split-K=2 -> 512 blocks
  hipLaunchKernelGGL((gemm128<0, 128>), dim3(8, 32, 2), dim3(256), 0, stream, act, wbf_down,
                     (void*)down_parts, (const unsigned short*)nullptr, 2048, 4096, 4096, 1024,
                     2048LL, 2048LL, 4194304LL);
  // s18: out = mh + sum(partials)
  hipLaunchKernelGGL(addn_f32_k, dim3(4096), dim3(256), 0, stream, mh, down_parts, 4194304LL, 2,
                     out, 1048576LL);
}